// Round 9
// baseline (4436.929 us; speedup 1.0000x reference)
//
#include <hip/hip_runtime.h>
#include <hip/hip_bf16.h>
#include <math.h>

using bf16 = __hip_bfloat16;
typedef short bf16x8 __attribute__((ext_vector_type(8)));
typedef float f32x4 __attribute__((ext_vector_type(4)));
typedef unsigned short u16x4 __attribute__((ext_vector_type(4)));

#define DEV __device__ __forceinline__

constexpr int BATCH = 2, SEQ = 4096, INPD = 1280, DM = 768, FFD = 3072;
constexpr int NL = 12, NH = 12, DHD = 64, NBLK = 64, NCLS = 2;
constexpr int MR = BATCH * SEQ;       // 8192 token rows
constexpr int QKVN = 3 * DM;          // 2304
constexpr int NJOBS = 62 + 16;        // interior blocks + 2 edges * 8 splits
constexpr int PARTF = 64 * 64 + 128;  // floats per edge partial (O + m + l)

DEV void gload_lds16(const void* g, void* l) {
  __builtin_amdgcn_global_load_lds(
      (const __attribute__((address_space(1))) unsigned int*)g,
      (__attribute__((address_space(3))) unsigned int*)l, 16, 0, 0);
}

DEV f32x4 mfma16(bf16x8 a, bf16x8 b, f32x4 c) {
  return __builtin_amdgcn_mfma_f32_16x16x32_bf16(a, b, c, 0, 0, 0);
}

DEV float b2f(unsigned short u) { return __uint_as_float((unsigned)u << 16); }
DEV unsigned short f2b(float x) {
  bf16 h = __float2bfloat16(x);
  return *(unsigned short*)&h;
}

// XCD-chunked bijective block swizzle (m204).
DEV int xcd_swizzle(int orig, int nwg) {
  int q = nwg >> 3, r = nwg & 7;
  int xcd = orig & 7, pos_ = orig >> 3;
  return (xcd < r ? xcd * (q + 1) : r * (q + 1) + (xcd - r) * q) + pos_;
}

// ----------------------------- f32 -> bf16 convert (16B stores) -----------------------------
__global__ void k_f32_to_bf16(const float* __restrict__ in, bf16* __restrict__ out, int n) {
  int i = (blockIdx.x * blockDim.x + threadIdx.x) * 8;
  int stride = gridDim.x * blockDim.x * 8;
  for (; i < n; i += stride) {
    float4 a = *(const float4*)(in + i);
    float4 b = *(const float4*)(in + i + 4);
    bf16 t8[8];
    t8[0] = __float2bfloat16(a.x); t8[1] = __float2bfloat16(a.y);
    t8[2] = __float2bfloat16(a.z); t8[3] = __float2bfloat16(a.w);
    t8[4] = __float2bfloat16(b.x); t8[5] = __float2bfloat16(b.y);
    t8[6] = __float2bfloat16(b.z); t8[7] = __float2bfloat16(b.w);
    *(bf16x8*)(out + i) = *(bf16x8*)t8;
  }
}

// ------------------------- weight transpose (K,N)f32 -> (N,K)bf16 -------------------------
DEV void tr32_tile(const float* __restrict__ src, bf16* __restrict__ dst,
                   int K, int N, int tile, float t[32][33], int tid) {
  int nt = N >> 5;
  int tk = tile / nt, tn = tile - tk * nt;
  int tx = tid & 31, ty = tid >> 5;
#pragma unroll
  for (int i = 0; i < 4; ++i)
    t[ty + 8 * i][tx] = src[(size_t)(tk * 32 + ty + 8 * i) * N + tn * 32 + tx];
  __syncthreads();
#pragma unroll
  for (int i = 0; i < 4; ++i)
    dst[(size_t)(tn * 32 + ty + 8 * i) * K + tk * 32 + tx] = __float2bfloat16(t[tx][ty + 8 * i]);
}

__global__ __launch_bounds__(256) void k_transpose_one(const float* __restrict__ src,
                                                       bf16* __restrict__ dst, int K, int N) {
  __shared__ float t[32][33];
  tr32_tile(src, dst, K, N, blockIdx.x, t, threadIdx.x);
}

__global__ __launch_bounds__(256) void k_transpose_layer(
    const float* __restrict__ Wq, const float* __restrict__ Wk,
    const float* __restrict__ Wv, const float* __restrict__ Wo,
    const float* __restrict__ W1, const float* __restrict__ W2,
    bf16* __restrict__ wqkvT, bf16* __restrict__ woT,
    bf16* __restrict__ w1T, bf16* __restrict__ w2T, int l) {
  __shared__ float t[32][33];
  int id = blockIdx.x;
  const float* src; bf16* dst; int K, N;
  if (id < 1728) {               // Wq,Wk,Wv -> concatenated (2304 x 768)
    int m = id / 576; id -= m * 576;
    src = (m == 0 ? Wq : m == 1 ? Wk : Wv) + (size_t)l * DM * DM;
    dst = wqkvT + (size_t)m * DM * DM; K = DM; N = DM;
  } else if (id < 2304) {
    id -= 1728; src = Wo + (size_t)l * DM * DM; dst = woT; K = DM; N = DM;
  } else if (id < 4608) {
    id -= 2304; src = W1 + (size_t)l * DM * FFD; dst = w1T; K = DM; N = FFD;
  } else {
    id -= 4608; src = W2 + (size_t)l * FFD * DM; dst = w2T; K = FFD; N = DM;
  }
  tr32_tile(src, dst, K, N, id, t, threadIdx.x);
}

// -------------------- 128^2 GEMM (2-phase, proven): C = A * BT^T --------------------
// For narrow-N shapes (O, W2, embed). Epilogues write bf16 raw (res fused in k_ln_res).
// EPI: 2 = +bias ; 3 = +bias +pos +tok (embed)
template <int EPI>
__global__ __launch_bounds__(256) void k_gemm(
    const bf16* __restrict__ A, const bf16* __restrict__ BT, int N, int K,
    const float* __restrict__ b0, const float* __restrict__ pos, const float* __restrict__ tok,
    bf16* __restrict__ Cb) {
  __shared__ __align__(16) bf16 lA[2][128 * 32];
  __shared__ __align__(16) bf16 lB[2][128 * 32];
  const int tid = threadIdx.x;
  const int gx = gridDim.x;
  const int tile = xcd_swizzle(blockIdx.y * gx + blockIdx.x, gx * gridDim.y);
  const int bx = tile % gx, by = tile / gx;
  const int bm = by * 128, bn = bx * 128;
  const int lane = tid & 63, wid = tid >> 6;
  const int wm = (wid >> 1) * 64, wn = (wid & 1) * 64;
  const int lr = lane & 15, lks = lane >> 4;
  const bf16* Abase = A + (size_t)bm * K;
  const bf16* Bbase = BT + (size_t)bn * K;

  auto stage = [&](int buf, int t) {
    int k0 = t << 5;
#pragma unroll
    for (int ss = 0; ss < 2; ++ss) {
      int seg = tid + ss * 256;
      int row = seg >> 2, slot = seg & 3;
      int kseg = slot ^ ((row >> 1) & 3);
      gload_lds16(Abase + (size_t)row * K + k0 + kseg * 8, &lA[buf][seg * 8]);
      gload_lds16(Bbase + (size_t)row * K + k0 + kseg * 8, &lB[buf][seg * 8]);
    }
  };

  f32x4 acc[4][4] = {};
  const int nt = K >> 5;
  stage(0, 0);
  __syncthreads();
  for (int t = 0; t < nt; ++t) {
    const int buf = t & 1;
    if (t + 1 < nt) stage(buf ^ 1, t + 1);
    bf16x8 af[4], bfr[4];
#pragma unroll
    for (int m = 0; m < 4; ++m) {
      int rr = wm + m * 16 + lr;
      af[m] = *(const bf16x8*)(&lA[buf][rr * 32 + ((lks ^ ((rr >> 1) & 3)) << 3)]);
    }
#pragma unroll
    for (int n = 0; n < 4; ++n) {
      int rr = wn + n * 16 + lr;
      bfr[n] = *(const bf16x8*)(&lB[buf][rr * 32 + ((lks ^ ((rr >> 1) & 3)) << 3)]);
    }
#pragma unroll
    for (int m = 0; m < 4; ++m)
#pragma unroll
      for (int n = 0; n < 4; ++n)
        acc[m][n] = mfma16(af[m], bfr[n], acc[m][n]);
    __syncthreads();
  }
  const int gq = lane >> 4;
#pragma unroll
  for (int m = 0; m < 4; ++m) {
#pragma unroll
    for (int n = 0; n < 4; ++n) {
      int gcol = bn + wn + n * 16 + lr;
      f32x4 v = acc[m][n];
#pragma unroll
      for (int rr = 0; rr < 4; ++rr) {
        int grow = bm + wm + m * 16 + gq * 4 + rr;
        float x = v[rr];
        if constexpr (EPI == 2) {
          x += b0[gcol];
        } else {
          x += b0[gcol] + pos[(size_t)(grow & (SEQ - 1)) * N + gcol] + tok[gcol];
        }
        Cb[(size_t)grow * N + gcol] = __float2bfloat16(x);
      }
    }
  }
}

// ------- 256x128 GEMM, 4 waves, per-wave 128x64 (LDS-read/FLOP halved): QKV, W1 -------
// Wave grid 2M x 2N; per K-step/wave: 12 ds_read_b128 (144cyc) vs 32 MFMA (160cyc) -> MFMA-led.
// acc = f32x4[8][4] = 128 VGPR; LDS 48KB dbuf; same 2-phase skeleton + swizzle as k_gemm.
// EPI: 0 = +segmented-bias(q/k/v) ; 1 = +bias, gelu
template <int EPI>
__global__ __launch_bounds__(256) void k_gemm_big(
    const bf16* __restrict__ A, const bf16* __restrict__ BT, int N, int K,
    const float* __restrict__ b0, const float* __restrict__ b1, const float* __restrict__ b2,
    bf16* __restrict__ Cb) {
  __shared__ __align__(16) bf16 lA[2][256 * 32];
  __shared__ __align__(16) bf16 lB[2][128 * 32];
  const int tid = threadIdx.x;
  const int gx = gridDim.x;
  const int tile = xcd_swizzle(blockIdx.y * gx + blockIdx.x, gx * gridDim.y);
  const int bx = tile % gx, by = tile / gx;
  const int bm = by * 256, bn = bx * 128;
  const int lane = tid & 63, wid = tid >> 6;
  const int wm = (wid >> 1) * 128, wn = (wid & 1) * 64;  // 2M x 2N waves, 128x64 each
  const int lr = lane & 15, lks = lane >> 4;
  const bf16* Abase = A + (size_t)bm * K;
  const bf16* Bbase = BT + (size_t)bn * K;

  // A: 1024 segs (256 rows x 4 k-slots) = 4/thread; B: 512 segs = 2/thread.
  auto stage = [&](int buf, int t) {
    int k0 = t << 5;
#pragma unroll
    for (int ss = 0; ss < 4; ++ss) {
      int seg = tid + ss * 256;
      int row = seg >> 2, slot = seg & 3;
      int kseg = slot ^ ((row >> 1) & 3);
      gload_lds16(Abase + (size_t)row * K + k0 + kseg * 8, &lA[buf][seg * 8]);
    }
#pragma unroll
    for (int ss = 0; ss < 2; ++ss) {
      int seg = tid + ss * 256;
      int row = seg >> 2, slot = seg & 3;
      int kseg = slot ^ ((row >> 1) & 3);
      gload_lds16(Bbase + (size_t)row * K + k0 + kseg * 8, &lB[buf][seg * 8]);
    }
  };

  f32x4 acc[8][4] = {};
  const int nt = K >> 5;
  stage(0, 0);
  __syncthreads();
  for (int t = 0; t < nt; ++t) {
    const int buf = t & 1;
    if (t + 1 < nt) stage(buf ^ 1, t + 1);
    bf16x8 af[8], bfr[4];
#pragma unroll
    for (int m = 0; m < 8; ++m) {
      int rr = wm + m * 16 + lr;
      af[m] = *(const bf16x8*)(&lA[buf][rr * 32 + ((lks ^ ((rr >> 1) & 3)) << 3)]);
    }
#pragma unroll
    for (int n = 0; n < 4; ++n) {
      int rr = wn + n * 16 + lr;
      bfr[n] = *(const bf16x8*)(&lB[buf][rr * 32 + ((lks ^ ((rr >> 1) & 3)) << 3)]);
    }
#pragma unroll
    for (int m = 0; m < 8; ++m)
#pragma unroll
      for (int n = 0; n < 4; ++n)
        acc[m][n] = mfma16(af[m], bfr[n], acc[m][n]);
    __syncthreads();
  }
  const int gq = lane >> 4;
#pragma unroll
  for (int m = 0; m < 8; ++m) {
#pragma unroll
    for (int n = 0; n < 4; ++n) {
      int gcol = bn + wn + n * 16 + lr;
      f32x4 v = acc[m][n];
#pragma unroll
      for (int rr = 0; rr < 4; ++rr) {
        int grow = bm + wm + m * 16 + gq * 4 + rr;
        float x = v[rr];
        if constexpr (EPI == 0) {
          int c = gcol; const float* bb = b0;
          if (c >= 2 * DM) { bb = b2; c -= 2 * DM; }
          else if (c >= DM) { bb = b1; c -= DM; }
          x += bb[c];
        } else {
          x += b0[gcol];
          x = 0.5f * x * (1.0f + erff(x * 0.70710678118654752f));
        }
        Cb[(size_t)grow * N + gcol] = __float2bfloat16(x);
      }
    }
  }
}

// ------- fused residual-add + LayerNorm, all-bf16 streams, wave-per-row, in-place safe -------
template <bool HASRES>
__global__ __launch_bounds__(256) void k_ln_res(
    const bf16* __restrict__ gout, const bf16* res,
    const float* __restrict__ g, const float* __restrict__ b,
    bf16* out) {
  const int wv = threadIdx.x >> 6, lane = threadIdx.x & 63;
  const int row = blockIdx.x * 4 + wv;
  const unsigned short* gp = (const unsigned short*)gout + (size_t)row * DM;
  const unsigned short* rp = (const unsigned short*)res + (size_t)row * DM;
  float v[12];
  float s = 0.f, s2 = 0.f;
#pragma unroll
  for (int i = 0; i < 3; ++i) {
    const int c = i * 256 + lane * 4;
    u16x4 a4 = *(const u16x4*)(gp + c);
    u16x4 r4;
    if constexpr (HASRES) r4 = *(const u16x4*)(rp + c);
#pragma unroll
    for (int k2 = 0; k2 < 4; ++k2) {
      float x = b2f(a4[k2]);
      if constexpr (HASRES) x += b2f(r4[k2]);
      v[i * 4 + k2] = x;
      s += x; s2 += x * x;
    }
  }
#pragma unroll
  for (int off = 1; off < 64; off <<= 1) {
    s += __shfl_xor(s, off);
    s2 += __shfl_xor(s2, off);
  }
  const float mean = s * (1.0f / DM);
  const float var = s2 * (1.0f / DM) - mean * mean;
  const float rs = rsqrtf(var + 1e-12f);
  unsigned short* op = (unsigned short*)out + (size_t)row * DM;
#pragma unroll
  for (int i = 0; i < 3; ++i) {
    const int c = i * 256 + lane * 4;
    float4 g4 = *(const float4*)(g + c);
    float4 b4 = *(const float4*)(b + c);
    u16x4 o4;
    o4[0] = f2b((v[i * 4 + 0] - mean) * rs * g4.x + b4.x);
    o4[1] = f2b((v[i * 4 + 1] - mean) * rs * g4.y + b4.y);
    o4[2] = f2b((v[i * 4 + 2] - mean) * rs * g4.z + b4.z);
    o4[3] = f2b((v[i * 4 + 3] - mean) * rs * g4.w + b4.w);
    *(u16x4*)(op + c) = o4;
  }
}

// ------------------- V transpose: qkv v-section (B,S,H,DH) -> vt (B,H,DH,S) -------------------
__global__ __launch_bounds__(256) void k_vt(const bf16* __restrict__ qkv, bf16* __restrict__ vt) {
  __shared__ unsigned short t[64][72];
  const int bh = blockIdx.y, t0 = blockIdx.x * 64;
  const int b = bh / NH, h = bh - b * NH;
  const int tid = threadIdx.x;
  const int rr = tid >> 2, cs = (tid & 3) * 16;
  const unsigned short* src = (const unsigned short*)qkv +
      (size_t)(b * SEQ + t0 + rr) * QKVN + 2 * DM + h * DHD + cs;
#pragma unroll
  for (int i = 0; i < 16; ++i) t[cs + i][rr] = src[i];
  __syncthreads();
  unsigned short* dst = (unsigned short*)vt + (size_t)(bh * DHD + rr) * SEQ + t0 + cs;
#pragma unroll
  for (int i = 0; i < 16; ++i) dst[i] = t[rr][cs + i];
}

// ----------------------------- block-sparse attention -----------------------------
__global__ __launch_bounds__(256) void k_attn(
    const bf16* __restrict__ qkv, const bf16* __restrict__ vt,
    const int* __restrict__ blk_idx,
    bf16* __restrict__ ctx, float* __restrict__ epart) {
  __shared__ __align__(16) bf16 sQ[64 * 64];
  __shared__ __align__(16) bf16 sK[2][64 * 64];
  __shared__ __align__(16) bf16 sV[2][64 * 64];
  __shared__ __align__(16) bf16 sP[4][16 * 64];
  const int job = blockIdx.x;
  const int b = job / (NH * NJOBS);
  const int rem = job - b * NH * NJOBS;
  const int h = rem / NJOBS;
  const int j = rem - h * NJOBS;
  const int tid = threadIdx.x, lane = tid & 63, w = tid >> 6;
  const int lr = lane & 15, lks = lane >> 4;

  const bool interior = (j < 62);
  int qblk, e = 0, split = 0;
  if (interior) qblk = j + 1;
  else { int tt = j - 62; e = tt >> 3; split = tt & 7; qblk = e ? NBLK - 1 : 0; }
  const int qt0 = qblk * 64;

  const int skip_pos = interior ? (j == 0 ? 2 : (j == 61 ? 4 : 8)) : 8;
  const int nkb = (skip_pos < 8) ? 7 : 8;
  auto kbi_of = [&](int i) {
    int kb = i + (i >= skip_pos ? 1 : 0);
    return interior ? blk_idx[j * 8 + kb] : split * 8 + kb;
  };

  const bf16* kbase0 = qkv + (size_t)b * SEQ * QKVN + DM + h * DHD;
  const bf16* vbase0 = vt + (size_t)((b * NH + h) * DHD) * SEQ;
  auto stageKV = [&](int buf, int kbi) {
    const int kt0 = kbi * 64;
#pragma unroll
    for (int ss = 0; ss < 2; ++ss) {
      int seg = tid + ss * 256;
      int row = seg >> 3, slot = seg & 7;
      int kseg = slot ^ (row & 7);
      gload_lds16(kbase0 + (size_t)(kt0 + row) * QKVN + kseg * 8, &sK[buf][seg * 8]);
      gload_lds16(vbase0 + (size_t)row * SEQ + kt0 + kseg * 8, &sV[buf][seg * 8]);
    }
  };

  {
    const bf16* qbase = qkv + (size_t)(b * SEQ + qt0) * QKVN + h * DHD;
#pragma unroll
    for (int ss = 0; ss < 2; ++ss) {
      int seg = tid + ss * 256;
      int row = seg >> 3, slot = seg & 7;
      int kseg = slot ^ (row & 7);
      gload_lds16(qbase + (size_t)row * QKVN + kseg * 8, sQ + seg * 8);
    }
  }
  stageKV(0, kbi_of(0));
  __syncthreads();
  bf16x8 aq[2];
#pragma unroll
  for (int kk = 0; kk < 2; ++kk) {
    int rq = w * 16 + lr;
    int slot = (kk * 4 + lks) ^ (rq & 7);
    aq[kk] = *(const bf16x8*)(sQ + rq * 64 + slot * 8);
  }

  float m_r[4], l_r[4];
  f32x4 o[4] = {};
#pragma unroll
  for (int r = 0; r < 4; ++r) { m_r[r] = -1e30f; l_r[r] = 0.f; }

  for (int i = 0; i < nkb; ++i) {
    const int buf = i & 1;
    if (i + 1 < nkb) stageKV(buf ^ 1, kbi_of(i + 1));
    f32x4 sfr[4];
#pragma unroll
    for (int n = 0; n < 4; ++n) {
      f32x4 z = {};
#pragma unroll
      for (int kk = 0; kk < 2; ++kk) {
        int rk = n * 16 + lr;
        int slot = (kk * 4 + lks) ^ (rk & 7);
        bf16x8 kf = *(const bf16x8*)(&sK[buf][rk * 64 + slot * 8]);
        z = mfma16(aq[kk], kf, z);
      }
      sfr[n] = z;
    }
#pragma unroll
    for (int n = 0; n < 4; ++n)
#pragma unroll
      for (int r = 0; r < 4; ++r) sfr[n][r] *= 0.125f;
    float alpha[4];
#pragma unroll
    for (int r = 0; r < 4; ++r) {
      float tmx = fmaxf(fmaxf(sfr[0][r], sfr[1][r]), fmaxf(sfr[2][r], sfr[3][r]));
#pragma unroll
      for (int off = 1; off < 16; off <<= 1) tmx = fmaxf(tmx, __shfl_xor(tmx, off));
      float mnew = fmaxf(m_r[r], tmx);
      alpha[r] = __expf(m_r[r] - mnew);
      m_r[r] = mnew;
    }
#pragma unroll
    for (int r = 0; r < 4; ++r) {
      float su = 0.f;
#pragma unroll
      for (int n = 0; n < 4; ++n) {
        float p = __expf(sfr[n][r] - m_r[r]);
        sfr[n][r] = p;
        su += p;
      }
#pragma unroll
      for (int off = 1; off < 16; off <<= 1) su += __shfl_xor(su, off);
      l_r[r] = l_r[r] * alpha[r] + su;
    }
#pragma unroll
    for (int n = 0; n < 4; ++n) {
#pragma unroll
      for (int r = 0; r < 4; ++r) {
        int prow = lks * 4 + r;
        int col = n * 16 + lr;
        int eo = prow * 64 + ((((col >> 3) ^ (prow & 7)) << 3) | (col & 7));
        sP[w][eo] = __float2bfloat16(sfr[n][r]);
      }
    }
#pragma unroll
    for (int n = 0; n < 4; ++n)
#pragma unroll
      for (int r = 0; r < 4; ++r) o[n][r] *= alpha[r];
    asm volatile("s_waitcnt lgkmcnt(0)" ::: "memory");
    __builtin_amdgcn_sched_barrier(0);
    bf16x8 pa[2];
#pragma unroll
    for (int kk = 0; kk < 2; ++kk) {
      int slot = (kk * 4 + lks) ^ (lr & 7);
      pa[kk] = *(const bf16x8*)(sP[w] + lr * 64 + slot * 8);
    }
#pragma unroll
    for (int n = 0; n < 4; ++n) {
#pragma unroll
      for (int kk = 0; kk < 2; ++kk) {
        int rv = n * 16 + lr;
        int slot = (kk * 4 + lks) ^ (rv & 7);
        bf16x8 vf = *(const bf16x8*)(&sV[buf][rv * 64 + slot * 8]);
        o[n] = mfma16(pa[kk], vf, o[n]);
      }
    }
    __syncthreads();
  }
  if (interior) {
#pragma unroll
    for (int r = 0; r < 4; ++r) {
      float inv = 1.0f / l_r[r];
      int tok = qt0 + w * 16 + lks * 4 + r;
#pragma unroll
      for (int n = 0; n < 4; ++n) {
        int col = h * DHD + n * 16 + lr;
        ctx[(size_t)(b * SEQ + tok) * DM + col] = __float2bfloat16(o[n][r] * inv);
      }
    }
  } else {
    float* base = epart + (size_t)((((b * NH + h) * 2 + e) * 8) + split) * PARTF;
#pragma unroll
    for (int r = 0; r < 4; ++r) {
      int qrow = w * 16 + lks * 4 + r;
#pragma unroll
      for (int n = 0; n < 4; ++n)
        base[qrow * 64 + n * 16 + lr] = o[n][r];
      if (lr == 0) { base[4096 + qrow] = m_r[r]; base[4096 + 64 + qrow] = l_r[r]; }
    }
  }
}

// ----------------------------- edge split-K combine -----------------------------
__global__ __launch_bounds__(256) void k_combine(const float* __restrict__ epart,
                                                 bf16* __restrict__ ctx) {
  const int bid = blockIdx.x;
  const int b = bid / (NH * 2);
  const int rem = bid - b * NH * 2;
  const int h = rem >> 1, e = rem & 1;
  const int tid = threadIdx.x;
  const int row = tid >> 2, cq = tid & 3;
  const float* base0 = epart + (size_t)(((b * NH + h) * 2 + e) * 8) * PARTF;
  float ms[8], ls[8], M = -1e30f;
#pragma unroll
  for (int s = 0; s < 8; ++s) {
    const float* bp = base0 + (size_t)s * PARTF;
    ms[s] = bp[4096 + row];
    ls[s] = bp[4096 + 64 + row];
    M = fmaxf(M, ms[s]);
  }
  float Lt = 0.f, accv[16];
#pragma unroll
  for (int i = 0; i < 16; ++i) accv[i] = 0.f;
#pragma unroll
  for (int s = 0; s < 8; ++s) {
    float wgt = __expf(ms[s] - M);
    Lt += ls[s] * wgt;
    const float* op = base0 + (size_t)s * PARTF + row * 64 + cq * 16;
#pragma unroll
    for (int i = 0; i < 16; ++i) accv[i] += op[i] * wgt;
  }
  float inv = 1.0f / Lt;
  int qblk = e ? NBLK - 1 : 0;
  int tok = qblk * 64 + row;
  bf16* cp = ctx + (size_t)(b * SEQ + tok) * DM + h * DHD + cq * 16;
#pragma unroll
  for (int i = 0; i < 16; ++i) cp[i] = __float2bfloat16(accv[i] * inv);
}

// ----------------------------- classifier: x[:,0,:] @ Wc + bc -----------------------------
__global__ void k_classifier(const bf16* __restrict__ xb, const float* __restrict__ Wc,
                             const float* __restrict__ bc, float* __restrict__ out) {
  const int tid = threadIdx.x, lane = tid & 63, wv = tid >> 6;
  const int b = wv >> 1, c = wv & 1;
  float s = 0.f;
  for (int d = lane; d < DM; d += 64)
    s += __bfloat162float(xb[(size_t)(b * SEQ) * DM + d]) * Wc[d * NCLS + c];
#pragma unroll
  for (int off = 32; off > 0; off >>= 1) s += __shfl_down(s, off);
  if (lane == 0) out[b * NCLS + c] = s + bc[c];
}

// ----------------------------- host launch -----------------------------
extern "C" void kernel_launch(void* const* d_in, const int* in_sizes, int n_in,
                              void* d_out, int out_size, void* d_ws, size_t ws_size,
                              hipStream_t stream) {
  const float* embeddings = (const float*)d_in[0];
  const float* Wp  = (const float*)d_in[2];
  const float* bp  = (const float*)d_in[3];
  const float* pos = (const float*)d_in[4];
  const float* tokv = (const float*)d_in[5];
  const float* lng = (const float*)d_in[6];
  const float* lnb = (const float*)d_in[7];
  const float* Wq  = (const float*)d_in[8];
  const float* bq  = (const float*)d_in[9];
  const float* Wk  = (const float*)d_in[10];
  const float* bk  = (const float*)d_in[11];
  const float* Wv  = (const float*)d_in[12];
  const float* bv  = (const float*)d_in[13];
  const float* Wo  = (const float*)d_in[14];
  const float* bo  = (const float*)d_in[15];
  const float* l1g = (const float*)d_in[16];
  const float* l1b = (const float*)d_in[17];
  const float* W1  = (const float*)d_in[18];
  const float* b1  = (const float*)d_in[19];
  const float* W2  = (const float*)d_in[20];
  const float* b2  = (const float*)d_in[21];
  const float* l2g = (const float*)d_in[22];
  const float* l2b = (const float*)d_in[23];
  const float* Wc  = (const float*)d_in[24];
  const float* bc  = (const float*)d_in[25];
  const int*  bidx = (const int*)d_in[26];
  (void)in_sizes; (void)n_in; (void)out_size; (void)ws_size;

  char* ws = (char*)d_ws;
  size_t off = 0;
  auto alloc = [&](size_t bytes) -> char* {
    char* p = ws + off;
    off += (bytes + 255) & ~(size_t)255;
    return p;
  };
  bf16*  embB  = (bf16*)alloc((size_t)MR * INPD * 2);
  bf16*  wpT   = (bf16*)alloc((size_t)DM * INPD * 2);
  bf16*  wqkvT = (bf16*)alloc((size_t)QKVN * DM * 2);
  bf16*  woT   = (bf16*)alloc((size_t)DM * DM * 2);
  bf16*  w1T   = (bf16*)alloc((size_t)FFD * DM * 2);
  bf16*  w2T   = (bf16*)alloc((size_t)DM * FFD * 2);
  bf16*  xb    = (bf16*)alloc((size_t)MR * DM * 2);   // residual stream (bf16)
  bf16*  gout  = (bf16*)alloc((size_t)MR * DM * 2);   // raw GEMM out (pre-LN)
  bf16*  qkvB  = (bf16*)alloc((size_t)MR * QKVN * 2);
  bf16*  vtB   = (bf16*)alloc((size_t)BATCH * NH * DHD * SEQ * 2);
  bf16*  ctxB  = (bf16*)alloc((size_t)MR * DM * 2);
  bf16*  hB    = (bf16*)alloc((size_t)MR * FFD * 2);
  float* epart = (float*)alloc((size_t)BATCH * NH * 2 * 8 * PARTF * 4);

  // embed: gout = emb @ Wp + bp + pos + tok (bf16); xb = LN(gout)
  k_f32_to_bf16<<<2048, 256, 0, stream>>>(embeddings, embB, MR * INPD);
  k_transpose_one<<<(INPD / 32) * (DM / 32), 256, 0, stream>>>(Wp, wpT, INPD, DM);
  k_gemm<3><<<dim3(DM / 128, MR / 128), 256, 0, stream>>>(embB, wpT, DM, INPD,
      bp, pos, tokv, gout);
  k_ln_res<false><<<MR / 4, 256, 0, stream>>>(gout, gout, lng, lnb, xb);

  for (int l = 0; l < NL; ++l) {
    k_transpose_layer<<<6912, 256, 0, stream>>>(Wq, Wk, Wv, Wo, W1, W2,
        wqkvT, woT, w1T, w2T, l);
    k_gemm_big<0><<<dim3(QKVN / 128, MR / 256), 256, 0, stream>>>(xb, wqkvT, QKVN, DM,
        bq + (size_t)l * DM, bk + (size_t)l * DM, bv + (size_t)l * DM, qkvB);
    k_vt<<<dim3(SEQ / 64, BATCH * NH), 256, 0, stream>>>(qkvB, vtB);
    k_attn<<<BATCH * NH * NJOBS, 256, 0, stream>>>(qkvB, vtB, bidx, ctxB, epart);
    k_combine<<<BATCH * NH * 2, 256, 0, stream>>>(epart, ctxB);
    k_gemm<2><<<dim3(DM / 128, MR / 128), 256, 0, stream>>>(ctxB, woT, DM, DM,
        bo + (size_t)l * DM, nullptr, nullptr, gout);
    k_ln_res<true><<<MR / 4, 256, 0, stream>>>(gout, xb,
        l1g + (size_t)l * DM, l1b + (size_t)l * DM, xb);
    k_gemm_big<1><<<dim3(FFD / 128, MR / 256), 256, 0, stream>>>(xb, w1T, FFD, DM,
        b1 + (size_t)l * FFD, nullptr, nullptr, hB);
    k_gemm<2><<<dim3(DM / 128, MR / 128), 256, 0, stream>>>(hB, w2T, DM, FFD,
        b2 + (size_t)l * DM, nullptr, nullptr, gout);
    k_ln_res<true><<<MR / 4, 256, 0, stream>>>(gout, xb,
        l2g + (size_t)l * DM, l2b + (size_t)l * DM, xb);
  }
  k_classifier<<<1, 256, 0, stream>>>(xb, Wc, bc, (float*)d_out);
}

// Round 10
// 3503.504 us; speedup vs baseline: 1.2664x; 1.2664x over previous
//
#include <hip/hip_runtime.h>
#include <hip/hip_bf16.h>
#include <math.h>

using bf16 = __hip_bfloat16;
typedef short bf16x8 __attribute__((ext_vector_type(8)));
typedef float f32x4 __attribute__((ext_vector_type(4)));
typedef unsigned short u16x4 __attribute__((ext_vector_type(4)));
typedef unsigned short u16x8 __attribute__((ext_vector_type(8)));
typedef short bf16x4v __attribute__((ext_vector_type(4)));

#define DEV __device__ __forceinline__

constexpr int BATCH = 2, SEQ = 4096, INPD = 1280, DM = 768, FFD = 3072;
constexpr int NL = 12, NH = 12, DHD = 64, NBLK = 64, NCLS = 2;
constexpr int MR = BATCH * SEQ;       // 8192 token rows
constexpr int QKVN = 3 * DM;          // 2304
constexpr int NJOBS = 62 + 16;        // interior blocks + 2 edges * 8 splits
constexpr int PARTF = 64 * 64 + 128;  // floats per edge partial (O + m + l)

DEV void gload_lds16(const void* g, void* l) {
  __builtin_amdgcn_global_load_lds(
      (const __attribute__((address_space(1))) unsigned int*)g,
      (__attribute__((address_space(3))) unsigned int*)l, 16, 0, 0);
}

DEV f32x4 mfma16(bf16x8 a, bf16x8 b, f32x4 c) {
  return __builtin_amdgcn_mfma_f32_16x16x32_bf16(a, b, c, 0, 0, 0);
}

DEV float b2f(unsigned short u) { return __uint_as_float((unsigned)u << 16); }
DEV unsigned short f2b(float x) {
  bf16 h = __float2bfloat16(x);
  return *(unsigned short*)&h;
}

// XCD-chunked bijective block swizzle (m204).
DEV int xcd_swizzle(int orig, int nwg) {
  int q = nwg >> 3, r = nwg & 7;
  int xcd = orig & 7, pos_ = orig >> 3;
  return (xcd < r ? xcd * (q + 1) : r * (q + 1) + (xcd - r) * q) + pos_;
}

// ----------------------------- f32 -> bf16 convert (16B stores) -----------------------------
__global__ void k_f32_to_bf16(const float* __restrict__ in, bf16* __restrict__ out, int n) {
  int i = (blockIdx.x * blockDim.x + threadIdx.x) * 8;
  int stride = gridDim.x * blockDim.x * 8;
  for (; i < n; i += stride) {
    float4 a = *(const float4*)(in + i);
    float4 b = *(const float4*)(in + i + 4);
    bf16 t8[8];
    t8[0] = __float2bfloat16(a.x); t8[1] = __float2bfloat16(a.y);
    t8[2] = __float2bfloat16(a.z); t8[3] = __float2bfloat16(a.w);
    t8[4] = __float2bfloat16(b.x); t8[5] = __float2bfloat16(b.y);
    t8[6] = __float2bfloat16(b.z); t8[7] = __float2bfloat16(b.w);
    *(bf16x8*)(out + i) = *(bf16x8*)t8;
  }
}

// ------------------------- weight transpose (K,N)f32 -> (N,K)bf16 -------------------------
// Vectorized: 1 float4 load + 1 bf16x4 (8B) store per thread per 32x32 tile.
// LDS pad 33: read banks = (kc+j+n)%32 -> ~2-way (free, m136).
DEV void tr32_tile(const float* __restrict__ src, bf16* __restrict__ dst,
                   int K, int N, int tile, float t[32][33], int tid) {
  int nt = N >> 5;
  int tk = tile / nt, tn = tile - tk * nt;
  {
    int k = tid >> 3, c4 = (tid & 7) << 2;
    float4 v = *(const float4*)(src + (size_t)(tk * 32 + k) * N + tn * 32 + c4);
    t[k][c4 + 0] = v.x; t[k][c4 + 1] = v.y; t[k][c4 + 2] = v.z; t[k][c4 + 3] = v.w;
  }
  __syncthreads();
  {
    int n = tid >> 3, kc = (tid & 7) << 2;
    bf16 o4[4];
    o4[0] = __float2bfloat16(t[kc + 0][n]);
    o4[1] = __float2bfloat16(t[kc + 1][n]);
    o4[2] = __float2bfloat16(t[kc + 2][n]);
    o4[3] = __float2bfloat16(t[kc + 3][n]);
    *(bf16x4v*)(dst + (size_t)(tn * 32 + n) * K + tk * 32 + kc) = *(bf16x4v*)o4;
  }
}

__global__ __launch_bounds__(256) void k_transpose_one(const float* __restrict__ src,
                                                       bf16* __restrict__ dst, int K, int N) {
  __shared__ float t[32][33];
  tr32_tile(src, dst, K, N, blockIdx.x, t, threadIdx.x);
}

__global__ __launch_bounds__(256) void k_transpose_layer(
    const float* __restrict__ Wq, const float* __restrict__ Wk,
    const float* __restrict__ Wv, const float* __restrict__ Wo,
    const float* __restrict__ W1, const float* __restrict__ W2,
    bf16* __restrict__ wqkvT, bf16* __restrict__ woT,
    bf16* __restrict__ w1T, bf16* __restrict__ w2T, int l) {
  __shared__ float t[32][33];
  int id = blockIdx.x;
  const float* src; bf16* dst; int K, N;
  if (id < 1728) {               // Wq,Wk,Wv -> concatenated (2304 x 768)
    int m = id / 576; id -= m * 576;
    src = (m == 0 ? Wq : m == 1 ? Wk : Wv) + (size_t)l * DM * DM;
    dst = wqkvT + (size_t)m * DM * DM; K = DM; N = DM;
  } else if (id < 2304) {
    id -= 1728; src = Wo + (size_t)l * DM * DM; dst = woT; K = DM; N = DM;
  } else if (id < 4608) {
    id -= 2304; src = W1 + (size_t)l * DM * FFD; dst = w1T; K = DM; N = FFD;
  } else {
    id -= 4608; src = W2 + (size_t)l * FFD * DM; dst = w2T; K = FFD; N = DM;
  }
  tr32_tile(src, dst, K, N, id, t, threadIdx.x);
}

// -------------------- 128^2 GEMM (2-phase, proven): C = A * BT^T --------------------
// For narrow-N shapes (O, W2, embed). Epilogues write bf16 raw (res fused in k_ln_res).
// EPI: 2 = +bias ; 3 = +bias +pos +tok (embed)
template <int EPI>
__global__ __launch_bounds__(256) void k_gemm(
    const bf16* __restrict__ A, const bf16* __restrict__ BT, int N, int K,
    const float* __restrict__ b0, const float* __restrict__ pos, const float* __restrict__ tok,
    bf16* __restrict__ Cb) {
  __shared__ __align__(16) bf16 lA[2][128 * 32];
  __shared__ __align__(16) bf16 lB[2][128 * 32];
  const int tid = threadIdx.x;
  const int gx = gridDim.x;
  const int tile = xcd_swizzle(blockIdx.y * gx + blockIdx.x, gx * gridDim.y);
  const int bx = tile % gx, by = tile / gx;
  const int bm = by * 128, bn = bx * 128;
  const int lane = tid & 63, wid = tid >> 6;
  const int wm = (wid >> 1) * 64, wn = (wid & 1) * 64;
  const int lr = lane & 15, lks = lane >> 4;
  const bf16* Abase = A + (size_t)bm * K;
  const bf16* Bbase = BT + (size_t)bn * K;

  auto stage = [&](int buf, int t) {
    int k0 = t << 5;
#pragma unroll
    for (int ss = 0; ss < 2; ++ss) {
      int seg = tid + ss * 256;
      int row = seg >> 2, slot = seg & 3;
      int kseg = slot ^ ((row >> 1) & 3);
      gload_lds16(Abase + (size_t)row * K + k0 + kseg * 8, &lA[buf][seg * 8]);
      gload_lds16(Bbase + (size_t)row * K + k0 + kseg * 8, &lB[buf][seg * 8]);
    }
  };

  f32x4 acc[4][4] = {};
  const int nt = K >> 5;
  stage(0, 0);
  __syncthreads();
  for (int t = 0; t < nt; ++t) {
    const int buf = t & 1;
    if (t + 1 < nt) stage(buf ^ 1, t + 1);
    bf16x8 af[4], bfr[4];
#pragma unroll
    for (int m = 0; m < 4; ++m) {
      int rr = wm + m * 16 + lr;
      af[m] = *(const bf16x8*)(&lA[buf][rr * 32 + ((lks ^ ((rr >> 1) & 3)) << 3)]);
    }
#pragma unroll
    for (int n = 0; n < 4; ++n) {
      int rr = wn + n * 16 + lr;
      bfr[n] = *(const bf16x8*)(&lB[buf][rr * 32 + ((lks ^ ((rr >> 1) & 3)) << 3)]);
    }
#pragma unroll
    for (int m = 0; m < 4; ++m)
#pragma unroll
      for (int n = 0; n < 4; ++n)
        acc[m][n] = mfma16(af[m], bfr[n], acc[m][n]);
    __syncthreads();
  }
  const int gq = lane >> 4;
#pragma unroll
  for (int m = 0; m < 4; ++m) {
#pragma unroll
    for (int n = 0; n < 4; ++n) {
      int gcol = bn + wn + n * 16 + lr;
      f32x4 v = acc[m][n];
#pragma unroll
      for (int rr = 0; rr < 4; ++rr) {
        int grow = bm + wm + m * 16 + gq * 4 + rr;
        float x = v[rr];
        if constexpr (EPI == 2) {
          x += b0[gcol];
        } else {
          x += b0[gcol] + pos[(size_t)(grow & (SEQ - 1)) * N + gcol] + tok[gcol];
        }
        Cb[(size_t)grow * N + gcol] = __float2bfloat16(x);
      }
    }
  }
}

// ------------- 256x128 GEMM (2-phase, 8 waves, r8 config): wide-N K=768 shapes -------------
// BM=256, BN=128, BK=32; wave grid 4M x 2N, per-wave 64x64; 3 gload_lds16/thread per K-step.
// EPI: 0 = +segmented-bias(q/k/v) ; 1 = +bias, gelu
template <int EPI>
__global__ __launch_bounds__(512) void k_gemm_big(
    const bf16* __restrict__ A, const bf16* __restrict__ BT, int N, int K,
    const float* __restrict__ b0, const float* __restrict__ b1, const float* __restrict__ b2,
    bf16* __restrict__ Cb) {
  __shared__ __align__(16) bf16 lA[2][256 * 32];
  __shared__ __align__(16) bf16 lB[2][128 * 32];
  const int tid = threadIdx.x;
  const int gx = gridDim.x;
  const int tile = xcd_swizzle(blockIdx.y * gx + blockIdx.x, gx * gridDim.y);
  const int bx = tile % gx, by = tile / gx;
  const int bm = by * 256, bn = bx * 128;
  const int lane = tid & 63, wid = tid >> 6;
  const int wm = (wid >> 1) * 64, wn = (wid & 1) * 64;  // 4M x 2N waves
  const int lr = lane & 15, lks = lane >> 4;
  const bf16* Abase = A + (size_t)bm * K;
  const bf16* Bbase = BT + (size_t)bn * K;

  // A: 1024 segs (256 rows x 4 slots) = 2/thread; B: 512 segs = 1/thread.
  auto stage = [&](int buf, int t) {
    int k0 = t << 5;
#pragma unroll
    for (int ss = 0; ss < 2; ++ss) {
      int seg = tid + ss * 512;
      int row = seg >> 2, slot = seg & 3;
      int kseg = slot ^ ((row >> 1) & 3);
      gload_lds16(Abase + (size_t)row * K + k0 + kseg * 8, &lA[buf][seg * 8]);
    }
    {
      int row = tid >> 2, slot = tid & 3;
      int kseg = slot ^ ((row >> 1) & 3);
      gload_lds16(Bbase + (size_t)row * K + k0 + kseg * 8, &lB[buf][tid * 8]);
    }
  };

  f32x4 acc[4][4] = {};
  const int nt = K >> 5;
  stage(0, 0);
  __syncthreads();
  for (int t = 0; t < nt; ++t) {
    const int buf = t & 1;
    if (t + 1 < nt) stage(buf ^ 1, t + 1);
    bf16x8 af[4], bfr[4];
#pragma unroll
    for (int m = 0; m < 4; ++m) {
      int rr = wm + m * 16 + lr;
      af[m] = *(const bf16x8*)(&lA[buf][rr * 32 + ((lks ^ ((rr >> 1) & 3)) << 3)]);
    }
#pragma unroll
    for (int n = 0; n < 4; ++n) {
      int rr = wn + n * 16 + lr;
      bfr[n] = *(const bf16x8*)(&lB[buf][rr * 32 + ((lks ^ ((rr >> 1) & 3)) << 3)]);
    }
#pragma unroll
    for (int m = 0; m < 4; ++m)
#pragma unroll
      for (int n = 0; n < 4; ++n)
        acc[m][n] = mfma16(af[m], bfr[n], acc[m][n]);
    __syncthreads();
  }
  const int gq = lane >> 4;
#pragma unroll
  for (int m = 0; m < 4; ++m) {
#pragma unroll
    for (int n = 0; n < 4; ++n) {
      int gcol = bn + wn + n * 16 + lr;
      f32x4 v = acc[m][n];
#pragma unroll
      for (int rr = 0; rr < 4; ++rr) {
        int grow = bm + wm + m * 16 + gq * 4 + rr;
        float x = v[rr];
        if constexpr (EPI == 0) {
          int c = gcol; const float* bb = b0;
          if (c >= 2 * DM) { bb = b2; c -= 2 * DM; }
          else if (c >= DM) { bb = b1; c -= DM; }
          x += bb[c];
        } else {
          x += b0[gcol];
          x = 0.5f * x * (1.0f + erff(x * 0.70710678118654752f));
        }
        Cb[(size_t)grow * N + gcol] = __float2bfloat16(x);
      }
    }
  }
}

// ------- fused residual-add + LayerNorm, all-bf16 streams, wave-per-row, in-place safe -------
template <bool HASRES>
__global__ __launch_bounds__(256) void k_ln_res(
    const bf16* __restrict__ gout, const bf16* res,
    const float* __restrict__ g, const float* __restrict__ b,
    bf16* out) {
  const int wv = threadIdx.x >> 6, lane = threadIdx.x & 63;
  const int row = blockIdx.x * 4 + wv;
  const unsigned short* gp = (const unsigned short*)gout + (size_t)row * DM;
  const unsigned short* rp = (const unsigned short*)res + (size_t)row * DM;
  float v[12];
  float s = 0.f, s2 = 0.f;
#pragma unroll
  for (int i = 0; i < 3; ++i) {
    const int c = i * 256 + lane * 4;
    u16x4 a4 = *(const u16x4*)(gp + c);
    u16x4 r4;
    if constexpr (HASRES) r4 = *(const u16x4*)(rp + c);
#pragma unroll
    for (int k2 = 0; k2 < 4; ++k2) {
      float x = b2f(a4[k2]);
      if constexpr (HASRES) x += b2f(r4[k2]);
      v[i * 4 + k2] = x;
      s += x; s2 += x * x;
    }
  }
#pragma unroll
  for (int off = 1; off < 64; off <<= 1) {
    s += __shfl_xor(s, off);
    s2 += __shfl_xor(s2, off);
  }
  const float mean = s * (1.0f / DM);
  const float var = s2 * (1.0f / DM) - mean * mean;
  const float rs = rsqrtf(var + 1e-12f);
  unsigned short* op = (unsigned short*)out + (size_t)row * DM;
#pragma unroll
  for (int i = 0; i < 3; ++i) {
    const int c = i * 256 + lane * 4;
    float4 g4 = *(const float4*)(g + c);
    float4 b4 = *(const float4*)(b + c);
    u16x4 o4;
    o4[0] = f2b((v[i * 4 + 0] - mean) * rs * g4.x + b4.x);
    o4[1] = f2b((v[i * 4 + 1] - mean) * rs * g4.y + b4.y);
    o4[2] = f2b((v[i * 4 + 2] - mean) * rs * g4.z + b4.z);
    o4[3] = f2b((v[i * 4 + 3] - mean) * rs * g4.w + b4.w);
    *(u16x4*)(op + c) = o4;
  }
}

// ------------------- V transpose: qkv v-section (B,S,H,DH) -> vt (B,H,DH,S) -------------------
// Global sides vectorized to 2x16B per thread; LDS scatter scalar (internal).
__global__ __launch_bounds__(256) void k_vt(const bf16* __restrict__ qkv, bf16* __restrict__ vt) {
  __shared__ unsigned short t[64][72];
  const int bh = blockIdx.y, t0 = blockIdx.x * 64;
  const int b = bh / NH, h = bh - b * NH;
  const int tid = threadIdx.x;
  const int rr = tid >> 2, cs = (tid & 3) * 16;
  const unsigned short* src = (const unsigned short*)qkv +
      (size_t)(b * SEQ + t0 + rr) * QKVN + 2 * DM + h * DHD + cs;
  u16x8 v0 = *(const u16x8*)(src);
  u16x8 v1 = *(const u16x8*)(src + 8);
#pragma unroll
  for (int i = 0; i < 8; ++i) { t[cs + i][rr] = v0[i]; t[cs + 8 + i][rr] = v1[i]; }
  __syncthreads();
  unsigned short* dst = (unsigned short*)vt + (size_t)(bh * DHD + rr) * SEQ + t0 + cs;
  u16x8 o0, o1;
#pragma unroll
  for (int i = 0; i < 8; ++i) { o0[i] = t[rr][cs + i]; o1[i] = t[rr][cs + 8 + i]; }
  *(u16x8*)(dst) = o0;
  *(u16x8*)(dst + 8) = o1;
}

// ----------------------------- block-sparse attention -----------------------------
__global__ __launch_bounds__(256) void k_attn(
    const bf16* __restrict__ qkv, const bf16* __restrict__ vt,
    const int* __restrict__ blk_idx,
    bf16* __restrict__ ctx, float* __restrict__ epart) {
  __shared__ __align__(16) bf16 sQ[64 * 64];
  __shared__ __align__(16) bf16 sK[2][64 * 64];
  __shared__ __align__(16) bf16 sV[2][64 * 64];
  __shared__ __align__(16) bf16 sP[4][16 * 64];
  const int job = blockIdx.x;
  const int b = job / (NH * NJOBS);
  const int rem = job - b * NH * NJOBS;
  const int h = rem / NJOBS;
  const int j = rem - h * NJOBS;
  const int tid = threadIdx.x, lane = tid & 63, w = tid >> 6;
  const int lr = lane & 15, lks = lane >> 4;

  const bool interior = (j < 62);
  int qblk, e = 0, split = 0;
  if (interior) qblk = j + 1;
  else { int tt = j - 62; e = tt >> 3; split = tt & 7; qblk = e ? NBLK - 1 : 0; }
  const int qt0 = qblk * 64;

  const int skip_pos = interior ? (j == 0 ? 2 : (j == 61 ? 4 : 8)) : 8;
  const int nkb = (skip_pos < 8) ? 7 : 8;
  auto kbi_of = [&](int i) {
    int kb = i + (i >= skip_pos ? 1 : 0);
    return interior ? blk_idx[j * 8 + kb] : split * 8 + kb;
  };

  const bf16* kbase0 = qkv + (size_t)b * SEQ * QKVN + DM + h * DHD;
  const bf16* vbase0 = vt + (size_t)((b * NH + h) * DHD) * SEQ;
  auto stageKV = [&](int buf, int kbi) {
    const int kt0 = kbi * 64;
#pragma unroll
    for (int ss = 0; ss < 2; ++ss) {
      int seg = tid + ss * 256;
      int row = seg >> 3, slot = seg & 7;
      int kseg = slot ^ (row & 7);
      gload_lds16(kbase0 + (size_t)(kt0 + row) * QKVN + kseg * 8, &sK[buf][seg * 8]);
      gload_lds16(vbase0 + (size_t)row * SEQ + kt0 + kseg * 8, &sV[buf][seg * 8]);
    }
  };

  {
    const bf16* qbase = qkv + (size_t)(b * SEQ + qt0) * QKVN + h * DHD;
#pragma unroll
    for (int ss = 0; ss < 2; ++ss) {
      int seg = tid + ss * 256;
      int row = seg >> 3, slot = seg & 7;
      int kseg = slot ^ (row & 7);
      gload_lds16(qbase + (size_t)row * QKVN + kseg * 8, sQ + seg * 8);
    }
  }
  stageKV(0, kbi_of(0));
  __syncthreads();
  bf16x8 aq[2];
#pragma unroll
  for (int kk = 0; kk < 2; ++kk) {
    int rq = w * 16 + lr;
    int slot = (kk * 4 + lks) ^ (rq & 7);
    aq[kk] = *(const bf16x8*)(sQ + rq * 64 + slot * 8);
  }

  float m_r[4], l_r[4];
  f32x4 o[4] = {};
#pragma unroll
  for (int r = 0; r < 4; ++r) { m_r[r] = -1e30f; l_r[r] = 0.f; }

  for (int i = 0; i < nkb; ++i) {
    const int buf = i & 1;
    if (i + 1 < nkb) stageKV(buf ^ 1, kbi_of(i + 1));
    f32x4 sfr[4];
#pragma unroll
    for (int n = 0; n < 4; ++n) {
      f32x4 z = {};
#pragma unroll
      for (int kk = 0; kk < 2; ++kk) {
        int rk = n * 16 + lr;
        int slot = (kk * 4 + lks) ^ (rk & 7);
        bf16x8 kf = *(const bf16x8*)(&sK[buf][rk * 64 + slot * 8]);
        z = mfma16(aq[kk], kf, z);
      }
      sfr[n] = z;
    }
#pragma unroll
    for (int n = 0; n < 4; ++n)
#pragma unroll
      for (int r = 0; r < 4; ++r) sfr[n][r] *= 0.125f;
    float alpha[4];
#pragma unroll
    for (int r = 0; r < 4; ++r) {
      float tmx = fmaxf(fmaxf(sfr[0][r], sfr[1][r]), fmaxf(sfr[2][r], sfr[3][r]));
#pragma unroll
      for (int off = 1; off < 16; off <<= 1) tmx = fmaxf(tmx, __shfl_xor(tmx, off));
      float mnew = fmaxf(m_r[r], tmx);
      alpha[r] = __expf(m_r[r] - mnew);
      m_r[r] = mnew;
    }
#pragma unroll
    for (int r = 0; r < 4; ++r) {
      float su = 0.f;
#pragma unroll
      for (int n = 0; n < 4; ++n) {
        float p = __expf(sfr[n][r] - m_r[r]);
        sfr[n][r] = p;
        su += p;
      }
#pragma unroll
      for (int off = 1; off < 16; off <<= 1) su += __shfl_xor(su, off);
      l_r[r] = l_r[r] * alpha[r] + su;
    }
#pragma unroll
    for (int n = 0; n < 4; ++n) {
#pragma unroll
      for (int r = 0; r < 4; ++r) {
        int prow = lks * 4 + r;
        int col = n * 16 + lr;
        int eo = prow * 64 + ((((col >> 3) ^ (prow & 7)) << 3) | (col & 7));
        sP[w][eo] = __float2bfloat16(sfr[n][r]);
      }
    }
#pragma unroll
    for (int n = 0; n < 4; ++n)
#pragma unroll
      for (int r = 0; r < 4; ++r) o[n][r] *= alpha[r];
    asm volatile("s_waitcnt lgkmcnt(0)" ::: "memory");
    __builtin_amdgcn_sched_barrier(0);
    bf16x8 pa[2];
#pragma unroll
    for (int kk = 0; kk < 2; ++kk) {
      int slot = (kk * 4 + lks) ^ (lr & 7);
      pa[kk] = *(const bf16x8*)(sP[w] + lr * 64 + slot * 8);
    }
#pragma unroll
    for (int n = 0; n < 4; ++n) {
#pragma unroll
      for (int kk = 0; kk < 2; ++kk) {
        int rv = n * 16 + lr;
        int slot = (kk * 4 + lks) ^ (rv & 7);
        bf16x8 vf = *(const bf16x8*)(&sV[buf][rv * 64 + slot * 8]);
        o[n] = mfma16(pa[kk], vf, o[n]);
      }
    }
    __syncthreads();
  }
  if (interior) {
#pragma unroll
    for (int r = 0; r < 4; ++r) {
      float inv = 1.0f / l_r[r];
      int tok = qt0 + w * 16 + lks * 4 + r;
#pragma unroll
      for (int n = 0; n < 4; ++n) {
        int col = h * DHD + n * 16 + lr;
        ctx[(size_t)(b * SEQ + tok) * DM + col] = __float2bfloat16(o[n][r] * inv);
      }
    }
  } else {
    float* base = epart + (size_t)((((b * NH + h) * 2 + e) * 8) + split) * PARTF;
#pragma unroll
    for (int r = 0; r < 4; ++r) {
      int qrow = w * 16 + lks * 4 + r;
#pragma unroll
      for (int n = 0; n < 4; ++n)
        base[qrow * 64 + n * 16 + lr] = o[n][r];
      if (lr == 0) { base[4096 + qrow] = m_r[r]; base[4096 + 64 + qrow] = l_r[r]; }
    }
  }
}

// ----------------------------- edge split-K combine -----------------------------
__global__ __launch_bounds__(256) void k_combine(const float* __restrict__ epart,
                                                 bf16* __restrict__ ctx) {
  const int bid = blockIdx.x;
  const int b = bid / (NH * 2);
  const int rem = bid - b * NH * 2;
  const int h = rem >> 1, e = rem & 1;
  const int tid = threadIdx.x;
  const int row = tid >> 2, cq = tid & 3;
  const float* base0 = epart + (size_t)(((b * NH + h) * 2 + e) * 8) * PARTF;
  float ms[8], ls[8], M = -1e30f;
#pragma unroll
  for (int s = 0; s < 8; ++s) {
    const float* bp = base0 + (size_t)s * PARTF;
    ms[s] = bp[4096 + row];
    ls[s] = bp[4096 + 64 + row];
    M = fmaxf(M, ms[s]);
  }
  float Lt = 0.f, accv[16];
#pragma unroll
  for (int i = 0; i < 16; ++i) accv[i] = 0.f;
#pragma unroll
  for (int s = 0; s < 8; ++s) {
    float wgt = __expf(ms[s] - M);
    Lt += ls[s] * wgt;
    const float* op = base0 + (size_t)s * PARTF + row * 64 + cq * 16;
#pragma unroll
    for (int i = 0; i < 16; ++i) accv[i] += op[i] * wgt;
  }
  float inv = 1.0f / Lt;
  int qblk = e ? NBLK - 1 : 0;
  int tok = qblk * 64 + row;
  bf16* cp = ctx + (size_t)(b * SEQ + tok) * DM + h * DHD + cq * 16;
#pragma unroll
  for (int i = 0; i < 16; ++i) cp[i] = __float2bfloat16(accv[i] * inv);
}

// ----------------------------- classifier: x[:,0,:] @ Wc + bc -----------------------------
__global__ void k_classifier(const bf16* __restrict__ xb, const float* __restrict__ Wc,
                             const float* __restrict__ bc, float* __restrict__ out) {
  const int tid = threadIdx.x, lane = tid & 63, wv = tid >> 6;
  const int b = wv >> 1, c = wv & 1;
  float s = 0.f;
  for (int d = lane; d < DM; d += 64)
    s += __bfloat162float(xb[(size_t)(b * SEQ) * DM + d]) * Wc[d * NCLS + c];
#pragma unroll
  for (int off = 32; off > 0; off >>= 1) s += __shfl_down(s, off);
  if (lane == 0) out[b * NCLS + c] = s + bc[c];
}

// ----------------------------- host launch -----------------------------
extern "C" void kernel_launch(void* const* d_in, const int* in_sizes, int n_in,
                              void* d_out, int out_size, void* d_ws, size_t ws_size,
                              hipStream_t stream) {
  const float* embeddings = (const float*)d_in[0];
  const float* Wp  = (const float*)d_in[2];
  const float* bp  = (const float*)d_in[3];
  const float* pos = (const float*)d_in[4];
  const float* tokv = (const float*)d_in[5];
  const float* lng = (const float*)d_in[6];
  const float* lnb = (const float*)d_in[7];
  const float* Wq  = (const float*)d_in[8];
  const float* bq  = (const float*)d_in[9];
  const float* Wk  = (const float*)d_in[10];
  const float* bk  = (const float*)d_in[11];
  const float* Wv  = (const float*)d_in[12];
  const float* bv  = (const float*)d_in[13];
  const float* Wo  = (const float*)d_in[14];
  const float* bo  = (const float*)d_in[15];
  const float* l1g = (const float*)d_in[16];
  const float* l1b = (const float*)d_in[17];
  const float* W1  = (const float*)d_in[18];
  const float* b1  = (const float*)d_in[19];
  const float* W2  = (const float*)d_in[20];
  const float* b2  = (const float*)d_in[21];
  const float* l2g = (const float*)d_in[22];
  const float* l2b = (const float*)d_in[23];
  const float* Wc  = (const float*)d_in[24];
  const float* bc  = (const float*)d_in[25];
  const int*  bidx = (const int*)d_in[26];
  (void)in_sizes; (void)n_in; (void)out_size; (void)ws_size;

  char* ws = (char*)d_ws;
  size_t off = 0;
  auto alloc = [&](size_t bytes) -> char* {
    char* p = ws + off;
    off += (bytes + 255) & ~(size_t)255;
    return p;
  };
  bf16*  embB  = (bf16*)alloc((size_t)MR * INPD * 2);
  bf16*  wpT   = (bf16*)alloc((size_t)DM * INPD * 2);
  bf16*  wqkvT = (bf16*)alloc((size_t)QKVN * DM * 2);
  bf16*  woT   = (bf16*)alloc((size_t)DM * DM * 2);
  bf16*  w1T   = (bf16*)alloc((size_t)FFD * DM * 2);
  bf16*  w2T   = (bf16*)alloc((size_t)DM * FFD * 2);
  bf16*  xb    = (bf16*)alloc((size_t)MR * DM * 2);   // residual stream (bf16)
  bf16*  gout  = (bf16*)alloc((size_t)MR * DM * 2);   // raw GEMM out (pre-LN)
  bf16*  qkvB  = (bf16*)alloc((size_t)MR * QKVN * 2);
  bf16*  vtB   = (bf16*)alloc((size_t)BATCH * NH * DHD * SEQ * 2);
  bf16*  ctxB  = (bf16*)alloc((size_t)MR * DM * 2);
  bf16*  hB    = (bf16*)alloc((size_t)MR * FFD * 2);
  float* epart = (float*)alloc((size_t)BATCH * NH * 2 * 8 * PARTF * 4);

  // embed: gout = emb @ Wp + bp + pos + tok (bf16); xb = LN(gout)
  k_f32_to_bf16<<<2048, 256, 0, stream>>>(embeddings, embB, MR * INPD);
  k_transpose_one<<<(INPD / 32) * (DM / 32), 256, 0, stream>>>(Wp, wpT, INPD, DM);
  k_gemm<3><<<dim3(DM / 128, MR / 128), 256, 0, stream>>>(embB, wpT, DM, INPD,
      bp, pos, tokv, gout);
  k_ln_res<false><<<MR / 4, 256, 0, stream>>>(gout, gout, lng, lnb, xb);

  for (int l = 0; l < NL; ++l) {
    k_transpose_layer<<<6912, 256, 0, stream>>>(Wq, Wk, Wv, Wo, W1, W2,
        wqkvT, woT, w1T, w2T, l);
    k_gemm_big<0><<<dim3(QKVN / 128, MR / 256), 512, 0, stream>>>(xb, wqkvT, QKVN, DM,
        bq + (size_t)l * DM, bk + (size_t)l * DM, bv + (size_t)l * DM, qkvB);
    k_vt<<<dim3(SEQ / 64, BATCH * NH), 256, 0, stream>>>(qkvB, vtB);
    k_attn<<<BATCH * NH * NJOBS, 256, 0, stream>>>(qkvB, vtB, bidx, ctxB, epart);
    k_combine<<<BATCH * NH * 2, 256, 0, stream>>>(epart, ctxB);
    k_gemm<2><<<dim3(DM / 128, MR / 128), 256, 0, stream>>>(ctxB, woT, DM, DM,
        bo + (size_t)l * DM, nullptr, nullptr, gout);
    k_ln_res<true><<<MR / 4, 256, 0, stream>>>(gout, xb,
        l1g + (size_t)l * DM, l1b + (size_t)l * DM, xb);
    k_gemm_big<1><<<dim3(FFD / 128, MR / 256), 512, 0, stream>>>(xb, w1T, FFD, DM,
        b1 + (size_t)l * FFD, nullptr, nullptr, hB);
    k_gemm<2><<<dim3(DM / 128, MR / 128), 256, 0, stream>>>(hB, w2T, DM, FFD,
        b2 + (size_t)l * DM, nullptr, nullptr, gout);
    k_ln_res<true><<<MR / 4, 256, 0, stream>>>(gout, xb,
        l2g + (size_t)l * DM, l2b + (size_t)l * DM, xb);
  }
  k_classifier<<<1, 256, 0, stream>>>(xb, Wc, bc, (float*)d_out);
}

// Round 11
// 3332.284 us; speedup vs baseline: 1.3315x; 1.0514x over previous
//
#include <hip/hip_runtime.h>
#include <hip/hip_bf16.h>
#include <math.h>

using bf16 = __hip_bfloat16;
typedef short bf16x8 __attribute__((ext_vector_type(8)));
typedef float f32x4 __attribute__((ext_vector_type(4)));
typedef unsigned short u16x4 __attribute__((ext_vector_type(4)));
typedef unsigned short u16x8 __attribute__((ext_vector_type(8)));
typedef short bf16x4v __attribute__((ext_vector_type(4)));

#define DEV __device__ __forceinline__

constexpr int BATCH = 2, SEQ = 4096, INPD = 1280, DM = 768, FFD = 3072;
constexpr int NL = 12, NH = 12, DHD = 64, NBLK = 64, NCLS = 2;
constexpr int MR = BATCH * SEQ;       // 8192 token rows
constexpr int QKVN = 3 * DM;          // 2304
constexpr int NJOBS = 62 + 16;        // interior blocks + 2 edges * 8 splits
constexpr int PARTF = 64 * 64 + 128;  // floats per edge partial (O + m + l)

DEV void gload_lds16(const void* g, void* l) {
  __builtin_amdgcn_global_load_lds(
      (const __attribute__((address_space(1))) unsigned int*)g,
      (__attribute__((address_space(3))) unsigned int*)l, 16, 0, 0);
}

DEV f32x4 mfma16(bf16x8 a, bf16x8 b, f32x4 c) {
  return __builtin_amdgcn_mfma_f32_16x16x32_bf16(a, b, c, 0, 0, 0);
}

DEV float b2f(unsigned short u) { return __uint_as_float((unsigned)u << 16); }
DEV unsigned short f2b(float x) {
  bf16 h = __float2bfloat16(x);
  return *(unsigned short*)&h;
}

// XCD-chunked bijective block swizzle (m204).
DEV int xcd_swizzle(int orig, int nwg) {
  int q = nwg >> 3, r = nwg & 7;
  int xcd = orig & 7, pos_ = orig >> 3;
  return (xcd < r ? xcd * (q + 1) : r * (q + 1) + (xcd - r) * q) + pos_;
}

// ----------------------------- f32 -> bf16 convert (16B stores) -----------------------------
__global__ void k_f32_to_bf16(const float* __restrict__ in, bf16* __restrict__ out, int n) {
  int i = (blockIdx.x * blockDim.x + threadIdx.x) * 8;
  int stride = gridDim.x * blockDim.x * 8;
  for (; i < n; i += stride) {
    float4 a = *(const float4*)(in + i);
    float4 b = *(const float4*)(in + i + 4);
    bf16 t8[8];
    t8[0] = __float2bfloat16(a.x); t8[1] = __float2bfloat16(a.y);
    t8[2] = __float2bfloat16(a.z); t8[3] = __float2bfloat16(a.w);
    t8[4] = __float2bfloat16(b.x); t8[5] = __float2bfloat16(b.y);
    t8[6] = __float2bfloat16(b.z); t8[7] = __float2bfloat16(b.w);
    *(bf16x8*)(out + i) = *(bf16x8*)t8;
  }
}

// ------------------------- weight transpose (K,N)f32 -> (N,K)bf16 -------------------------
DEV void tr32_tile(const float* __restrict__ src, bf16* __restrict__ dst,
                   int K, int N, int tile, float t[32][33], int tid) {
  int nt = N >> 5;
  int tk = tile / nt, tn = tile - tk * nt;
  {
    int k = tid >> 3, c4 = (tid & 7) << 2;
    float4 v = *(const float4*)(src + (size_t)(tk * 32 + k) * N + tn * 32 + c4);
    t[k][c4 + 0] = v.x; t[k][c4 + 1] = v.y; t[k][c4 + 2] = v.z; t[k][c4 + 3] = v.w;
  }
  __syncthreads();
  {
    int n = tid >> 3, kc = (tid & 7) << 2;
    bf16 o4[4];
    o4[0] = __float2bfloat16(t[kc + 0][n]);
    o4[1] = __float2bfloat16(t[kc + 1][n]);
    o4[2] = __float2bfloat16(t[kc + 2][n]);
    o4[3] = __float2bfloat16(t[kc + 3][n]);
    *(bf16x4v*)(dst + (size_t)(tn * 32 + n) * K + tk * 32 + kc) = *(bf16x4v*)o4;
  }
}

__global__ __launch_bounds__(256) void k_transpose_one(const float* __restrict__ src,
                                                       bf16* __restrict__ dst, int K, int N) {
  __shared__ float t[32][33];
  tr32_tile(src, dst, K, N, blockIdx.x, t, threadIdx.x);
}

__global__ __launch_bounds__(256) void k_transpose_layer(
    const float* __restrict__ Wq, const float* __restrict__ Wk,
    const float* __restrict__ Wv, const float* __restrict__ Wo,
    const float* __restrict__ W1, const float* __restrict__ W2,
    bf16* __restrict__ wqkvT, bf16* __restrict__ woT,
    bf16* __restrict__ w1T, bf16* __restrict__ w2T, int l) {
  __shared__ float t[32][33];
  int id = blockIdx.x;
  const float* src; bf16* dst; int K, N;
  if (id < 1728) {               // Wq,Wk,Wv -> concatenated (2304 x 768)
    int m = id / 576; id -= m * 576;
    src = (m == 0 ? Wq : m == 1 ? Wk : Wv) + (size_t)l * DM * DM;
    dst = wqkvT + (size_t)m * DM * DM; K = DM; N = DM;
  } else if (id < 2304) {
    id -= 1728; src = Wo + (size_t)l * DM * DM; dst = woT; K = DM; N = DM;
  } else if (id < 4608) {
    id -= 2304; src = W1 + (size_t)l * DM * FFD; dst = w1T; K = DM; N = FFD;
  } else {
    id -= 4608; src = W2 + (size_t)l * FFD * DM; dst = w2T; K = FFD; N = DM;
  }
  tr32_tile(src, dst, K, N, id, t, threadIdx.x);
}

// -------------------- 128^2 GEMM (2-phase, proven): C = A * BT^T --------------------
// EPI: 2 = +bias ; 3 = +bias +pos +tok (embed)
template <int EPI>
__global__ __launch_bounds__(256) void k_gemm(
    const bf16* __restrict__ A, const bf16* __restrict__ BT, int N, int K,
    const float* __restrict__ b0, const float* __restrict__ pos, const float* __restrict__ tok,
    bf16* __restrict__ Cb) {
  __shared__ __align__(16) bf16 lA[2][128 * 32];
  __shared__ __align__(16) bf16 lB[2][128 * 32];
  const int tid = threadIdx.x;
  const int gx = gridDim.x;
  const int tile = xcd_swizzle(blockIdx.y * gx + blockIdx.x, gx * gridDim.y);
  const int bx = tile % gx, by = tile / gx;
  const int bm = by * 128, bn = bx * 128;
  const int lane = tid & 63, wid = tid >> 6;
  const int wm = (wid >> 1) * 64, wn = (wid & 1) * 64;
  const int lr = lane & 15, lks = lane >> 4;
  const bf16* Abase = A + (size_t)bm * K;
  const bf16* Bbase = BT + (size_t)bn * K;

  auto stage = [&](int buf, int t) {
    int k0 = t << 5;
#pragma unroll
    for (int ss = 0; ss < 2; ++ss) {
      int seg = tid + ss * 256;
      int row = seg >> 2, slot = seg & 3;
      int kseg = slot ^ ((row >> 1) & 3);
      gload_lds16(Abase + (size_t)row * K + k0 + kseg * 8, &lA[buf][seg * 8]);
      gload_lds16(Bbase + (size_t)row * K + k0 + kseg * 8, &lB[buf][seg * 8]);
    }
  };

  f32x4 acc[4][4] = {};
  const int nt = K >> 5;
  stage(0, 0);
  __syncthreads();
  for (int t = 0; t < nt; ++t) {
    const int buf = t & 1;
    if (t + 1 < nt) stage(buf ^ 1, t + 1);
    bf16x8 af[4], bfr[4];
#pragma unroll
    for (int m = 0; m < 4; ++m) {
      int rr = wm + m * 16 + lr;
      af[m] = *(const bf16x8*)(&lA[buf][rr * 32 + ((lks ^ ((rr >> 1) & 3)) << 3)]);
    }
#pragma unroll
    for (int n = 0; n < 4; ++n) {
      int rr = wn + n * 16 + lr;
      bfr[n] = *(const bf16x8*)(&lB[buf][rr * 32 + ((lks ^ ((rr >> 1) & 3)) << 3)]);
    }
#pragma unroll
    for (int m = 0; m < 4; ++m)
#pragma unroll
      for (int n = 0; n < 4; ++n)
        acc[m][n] = mfma16(af[m], bfr[n], acc[m][n]);
    __syncthreads();
  }
  const int gq = lane >> 4;
#pragma unroll
  for (int m = 0; m < 4; ++m) {
#pragma unroll
    for (int n = 0; n < 4; ++n) {
      int gcol = bn + wn + n * 16 + lr;
      f32x4 v = acc[m][n];
#pragma unroll
      for (int rr = 0; rr < 4; ++rr) {
        int grow = bm + wm + m * 16 + gq * 4 + rr;
        float x = v[rr];
        if constexpr (EPI == 2) {
          x += b0[gcol];
        } else {
          x += b0[gcol] + pos[(size_t)(grow & (SEQ - 1)) * N + gcol] + tok[gcol];
        }
        Cb[(size_t)grow * N + gcol] = __float2bfloat16(x);
      }
    }
  }
}

// ------------- 256x128 GEMM (2-phase, 8 waves, r8 config): wide-N K=768 shapes -------------
// EPI 0 (QKV): Q,K parts -> qkv buffer; V part written DIRECTLY TRANSPOSED into vt
// (B,H,DH,S) via one 8B store per fragment (4 consecutive tokens at one d).
// EPI 1 (W1): +bias, gelu -> Cb.
template <int EPI>
__global__ __launch_bounds__(512) void k_gemm_big(
    const bf16* __restrict__ A, const bf16* __restrict__ BT, int N, int K,
    const float* __restrict__ b0, const float* __restrict__ b1, const float* __restrict__ b2,
    bf16* __restrict__ vt, bf16* __restrict__ Cb) {
  __shared__ __align__(16) bf16 lA[2][256 * 32];
  __shared__ __align__(16) bf16 lB[2][128 * 32];
  const int tid = threadIdx.x;
  const int gx = gridDim.x;
  const int tile = xcd_swizzle(blockIdx.y * gx + blockIdx.x, gx * gridDim.y);
  const int bx = tile % gx, by = tile / gx;
  const int bm = by * 256, bn = bx * 128;
  const int lane = tid & 63, wid = tid >> 6;
  const int wm = (wid >> 1) * 64, wn = (wid & 1) * 64;  // 4M x 2N waves
  const int lr = lane & 15, lks = lane >> 4;
  const bf16* Abase = A + (size_t)bm * K;
  const bf16* Bbase = BT + (size_t)bn * K;

  auto stage = [&](int buf, int t) {
    int k0 = t << 5;
#pragma unroll
    for (int ss = 0; ss < 2; ++ss) {
      int seg = tid + ss * 512;
      int row = seg >> 2, slot = seg & 3;
      int kseg = slot ^ ((row >> 1) & 3);
      gload_lds16(Abase + (size_t)row * K + k0 + kseg * 8, &lA[buf][seg * 8]);
    }
    {
      int row = tid >> 2, slot = tid & 3;
      int kseg = slot ^ ((row >> 1) & 3);
      gload_lds16(Bbase + (size_t)row * K + k0 + kseg * 8, &lB[buf][tid * 8]);
    }
  };

  f32x4 acc[4][4] = {};
  const int nt = K >> 5;
  stage(0, 0);
  __syncthreads();
  for (int t = 0; t < nt; ++t) {
    const int buf = t & 1;
    if (t + 1 < nt) stage(buf ^ 1, t + 1);
    bf16x8 af[4], bfr[4];
#pragma unroll
    for (int m = 0; m < 4; ++m) {
      int rr = wm + m * 16 + lr;
      af[m] = *(const bf16x8*)(&lA[buf][rr * 32 + ((lks ^ ((rr >> 1) & 3)) << 3)]);
    }
#pragma unroll
    for (int n = 0; n < 4; ++n) {
      int rr = wn + n * 16 + lr;
      bfr[n] = *(const bf16x8*)(&lB[buf][rr * 32 + ((lks ^ ((rr >> 1) & 3)) << 3)]);
    }
#pragma unroll
    for (int m = 0; m < 4; ++m)
#pragma unroll
      for (int n = 0; n < 4; ++n)
        acc[m][n] = mfma16(af[m], bfr[n], acc[m][n]);
    __syncthreads();
  }
  const int gq = lane >> 4;
#pragma unroll
  for (int m = 0; m < 4; ++m) {
#pragma unroll
    for (int n = 0; n < 4; ++n) {
      int gcol = bn + wn + n * 16 + lr;
      int grow0 = bm + wm + m * 16 + gq * 4;
      f32x4 v = acc[m][n];
      if constexpr (EPI == 0) {
        if (gcol < 2 * DM) {           // Q or K section -> qkv buffer
          const float* bb = (gcol < DM) ? b0 : b1;
          float bias = bb[(gcol < DM) ? gcol : gcol - DM];
#pragma unroll
          for (int rr = 0; rr < 4; ++rr)
            Cb[(size_t)(grow0 + rr) * N + gcol] = __float2bfloat16(v[rr] + bias);
        } else {                       // V section -> transposed into vt (B,H,DH,S)
          int c = gcol - 2 * DM;
          float bias = b2[c];
          int h = c >> 6, d = c & 63;
          int bq_ = grow0 >> 12, s = grow0 & (SEQ - 1);  // tile never straddles batch
          bf16 o4[4];
#pragma unroll
          for (int rr = 0; rr < 4; ++rr) o4[rr] = __float2bfloat16(v[rr] + bias);
          *(bf16x4v*)(vt + ((size_t)((bq_ * NH + h) * DHD + d)) * SEQ + s) = *(bf16x4v*)o4;
        }
      } else {
        float bias = b0[gcol];
#pragma unroll
        for (int rr = 0; rr < 4; ++rr) {
          float x = v[rr] + bias;
          x = 0.5f * x * (1.0f + erff(x * 0.70710678118654752f));
          Cb[(size_t)(grow0 + rr) * N + gcol] = __float2bfloat16(x);
        }
      }
    }
  }
}

// ------- fused residual-add + LayerNorm, all-bf16 streams, wave-per-row, in-place safe -------
template <bool HASRES>
__global__ __launch_bounds__(256) void k_ln_res(
    const bf16* __restrict__ gout, const bf16* res,
    const float* __restrict__ g, const float* __restrict__ b,
    bf16* out) {
  const int wv = threadIdx.x >> 6, lane = threadIdx.x & 63;
  const int row = blockIdx.x * 4 + wv;
  const unsigned short* gp = (const unsigned short*)gout + (size_t)row * DM;
  const unsigned short* rp = (const unsigned short*)res + (size_t)row * DM;
  float v[12];
  float s = 0.f, s2 = 0.f;
#pragma unroll
  for (int i = 0; i < 3; ++i) {
    const int c = i * 256 + lane * 4;
    u16x4 a4 = *(const u16x4*)(gp + c);
    u16x4 r4;
    if constexpr (HASRES) r4 = *(const u16x4*)(rp + c);
#pragma unroll
    for (int k2 = 0; k2 < 4; ++k2) {
      float x = b2f(a4[k2]);
      if constexpr (HASRES) x += b2f(r4[k2]);
      v[i * 4 + k2] = x;
      s += x; s2 += x * x;
    }
  }
#pragma unroll
  for (int off = 1; off < 64; off <<= 1) {
    s += __shfl_xor(s, off);
    s2 += __shfl_xor(s2, off);
  }
  const float mean = s * (1.0f / DM);
  const float var = s2 * (1.0f / DM) - mean * mean;
  const float rs = rsqrtf(var + 1e-12f);
  unsigned short* op = (unsigned short*)out + (size_t)row * DM;
#pragma unroll
  for (int i = 0; i < 3; ++i) {
    const int c = i * 256 + lane * 4;
    float4 g4 = *(const float4*)(g + c);
    float4 b4 = *(const float4*)(b + c);
    u16x4 o4;
    o4[0] = f2b((v[i * 4 + 0] - mean) * rs * g4.x + b4.x);
    o4[1] = f2b((v[i * 4 + 1] - mean) * rs * g4.y + b4.y);
    o4[2] = f2b((v[i * 4 + 2] - mean) * rs * g4.z + b4.z);
    o4[3] = f2b((v[i * 4 + 3] - mean) * rs * g4.w + b4.w);
    *(u16x4*)(op + c) = o4;
  }
}

// ----------------------------- block-sparse attention -----------------------------
// nj/jbase select the job window: full layers nj=78 jbase=0; last layer nj=8 jbase=62 (e=0).
__global__ __launch_bounds__(256) void k_attn(
    const bf16* __restrict__ qkv, const bf16* __restrict__ vt,
    const int* __restrict__ blk_idx,
    bf16* __restrict__ ctx, float* __restrict__ epart, int nj, int jbase) {
  __shared__ __align__(16) bf16 sQ[64 * 64];
  __shared__ __align__(16) bf16 sK[2][64 * 64];
  __shared__ __align__(16) bf16 sV[2][64 * 64];
  __shared__ __align__(16) bf16 sP[4][16 * 64];
  const int job = blockIdx.x;
  const int b = job / (NH * nj);
  const int rem = job - b * NH * nj;
  const int h = rem / nj;
  const int j = jbase + (rem - h * nj);
  const int tid = threadIdx.x, lane = tid & 63, w = tid >> 6;
  const int lr = lane & 15, lks = lane >> 4;

  const bool interior = (j < 62);
  int qblk, e = 0, split = 0;
  if (interior) qblk = j + 1;
  else { int tt = j - 62; e = tt >> 3; split = tt & 7; qblk = e ? NBLK - 1 : 0; }
  const int qt0 = qblk * 64;

  const int skip_pos = interior ? (j == 0 ? 2 : (j == 61 ? 4 : 8)) : 8;
  const int nkb = (skip_pos < 8) ? 7 : 8;
  auto kbi_of = [&](int i) {
    int kb = i + (i >= skip_pos ? 1 : 0);
    return interior ? blk_idx[j * 8 + kb] : split * 8 + kb;
  };

  const bf16* kbase0 = qkv + (size_t)b * SEQ * QKVN + DM + h * DHD;
  const bf16* vbase0 = vt + (size_t)((b * NH + h) * DHD) * SEQ;
  auto stageKV = [&](int buf, int kbi) {
    const int kt0 = kbi * 64;
#pragma unroll
    for (int ss = 0; ss < 2; ++ss) {
      int seg = tid + ss * 256;
      int row = seg >> 3, slot = seg & 7;
      int kseg = slot ^ (row & 7);
      gload_lds16(kbase0 + (size_t)(kt0 + row) * QKVN + kseg * 8, &sK[buf][seg * 8]);
      gload_lds16(vbase0 + (size_t)row * SEQ + kt0 + kseg * 8, &sV[buf][seg * 8]);
    }
  };

  {
    const bf16* qbase = qkv + (size_t)(b * SEQ + qt0) * QKVN + h * DHD;
#pragma unroll
    for (int ss = 0; ss < 2; ++ss) {
      int seg = tid + ss * 256;
      int row = seg >> 3, slot = seg & 7;
      int kseg = slot ^ (row & 7);
      gload_lds16(qbase + (size_t)row * QKVN + kseg * 8, sQ + seg * 8);
    }
  }
  stageKV(0, kbi_of(0));
  __syncthreads();
  bf16x8 aq[2];
#pragma unroll
  for (int kk = 0; kk < 2; ++kk) {
    int rq = w * 16 + lr;
    int slot = (kk * 4 + lks) ^ (rq & 7);
    aq[kk] = *(const bf16x8*)(sQ + rq * 64 + slot * 8);
  }

  float m_r[4], l_r[4];
  f32x4 o[4] = {};
#pragma unroll
  for (int r = 0; r < 4; ++r) { m_r[r] = -1e30f; l_r[r] = 0.f; }

  for (int i = 0; i < nkb; ++i) {
    const int buf = i & 1;
    if (i + 1 < nkb) stageKV(buf ^ 1, kbi_of(i + 1));
    f32x4 sfr[4];
#pragma unroll
    for (int n = 0; n < 4; ++n) {
      f32x4 z = {};
#pragma unroll
      for (int kk = 0; kk < 2; ++kk) {
        int rk = n * 16 + lr;
        int slot = (kk * 4 + lks) ^ (rk & 7);
        bf16x8 kf = *(const bf16x8*)(&sK[buf][rk * 64 + slot * 8]);
        z = mfma16(aq[kk], kf, z);
      }
      sfr[n] = z;
    }
#pragma unroll
    for (int n = 0; n < 4; ++n)
#pragma unroll
      for (int r = 0; r < 4; ++r) sfr[n][r] *= 0.125f;
    float alpha[4];
#pragma unroll
    for (int r = 0; r < 4; ++r) {
      float tmx = fmaxf(fmaxf(sfr[0][r], sfr[1][r]), fmaxf(sfr[2][r], sfr[3][r]));
#pragma unroll
      for (int off = 1; off < 16; off <<= 1) tmx = fmaxf(tmx, __shfl_xor(tmx, off));
      float mnew = fmaxf(m_r[r], tmx);
      alpha[r] = __expf(m_r[r] - mnew);
      m_r[r] = mnew;
    }
#pragma unroll
    for (int r = 0; r < 4; ++r) {
      float su = 0.f;
#pragma unroll
      for (int n = 0; n < 4; ++n) {
        float p = __expf(sfr[n][r] - m_r[r]);
        sfr[n][r] = p;
        su += p;
      }
#pragma unroll
      for (int off = 1; off < 16; off <<= 1) su += __shfl_xor(su, off);
      l_r[r] = l_r[r] * alpha[r] + su;
    }
#pragma unroll
    for (int n = 0; n < 4; ++n) {
#pragma unroll
      for (int r = 0; r < 4; ++r) {
        int prow = lks * 4 + r;
        int col = n * 16 + lr;
        int eo = prow * 64 + ((((col >> 3) ^ (prow & 7)) << 3) | (col & 7));
        sP[w][eo] = __float2bfloat16(sfr[n][r]);
      }
    }
#pragma unroll
    for (int n = 0; n < 4; ++n)
#pragma unroll
      for (int r = 0; r < 4; ++r) o[n][r] *= alpha[r];
    asm volatile("s_waitcnt lgkmcnt(0)" ::: "memory");
    __builtin_amdgcn_sched_barrier(0);
    bf16x8 pa[2];
#pragma unroll
    for (int kk = 0; kk < 2; ++kk) {
      int slot = (kk * 4 + lks) ^ (lr & 7);
      pa[kk] = *(const bf16x8*)(sP[w] + lr * 64 + slot * 8);
    }
#pragma unroll
    for (int n = 0; n < 4; ++n) {
#pragma unroll
      for (int kk = 0; kk < 2; ++kk) {
        int rv = n * 16 + lr;
        int slot = (kk * 4 + lks) ^ (rv & 7);
        bf16x8 vf = *(const bf16x8*)(&sV[buf][rv * 64 + slot * 8]);
        o[n] = mfma16(pa[kk], vf, o[n]);
      }
    }
    __syncthreads();
  }
  if (interior) {
#pragma unroll
    for (int r = 0; r < 4; ++r) {
      float inv = 1.0f / l_r[r];
      int tok = qt0 + w * 16 + lks * 4 + r;
#pragma unroll
      for (int n = 0; n < 4; ++n) {
        int col = h * DHD + n * 16 + lr;
        ctx[(size_t)(b * SEQ + tok) * DM + col] = __float2bfloat16(o[n][r] * inv);
      }
    }
  } else {
    float* base = epart + (size_t)((((b * NH + h) * 2 + e) * 8) + split) * PARTF;
#pragma unroll
    for (int r = 0; r < 4; ++r) {
      int qrow = w * 16 + lks * 4 + r;
#pragma unroll
      for (int n = 0; n < 4; ++n)
        base[qrow * 64 + n * 16 + lr] = o[n][r];
      if (lr == 0) { base[4096 + qrow] = m_r[r]; base[4096 + 64 + qrow] = l_r[r]; }
    }
  }
}

// ----------------------------- edge split-K combine (ne edges) -----------------------------
__global__ __launch_bounds__(256) void k_combine(const float* __restrict__ epart,
                                                 bf16* __restrict__ ctx, int ne) {
  const int bid = blockIdx.x;  // B*H*ne
  const int b = bid / (NH * ne);
  const int rem = bid - b * NH * ne;
  const int h = rem / ne, e = rem - (rem / ne) * ne;
  const int tid = threadIdx.x;
  const int row = tid >> 2, cq = tid & 3;
  const float* base0 = epart + (size_t)(((b * NH + h) * 2 + e) * 8) * PARTF;
  float ms[8], ls[8], M = -1e30f;
#pragma unroll
  for (int s = 0; s < 8; ++s) {
    const float* bp = base0 + (size_t)s * PARTF;
    ms[s] = bp[4096 + row];
    ls[s] = bp[4096 + 64 + row];
    M = fmaxf(M, ms[s]);
  }
  float Lt = 0.f, accv[16];
#pragma unroll
  for (int i = 0; i < 16; ++i) accv[i] = 0.f;
#pragma unroll
  for (int s = 0; s < 8; ++s) {
    float wgt = __expf(ms[s] - M);
    Lt += ls[s] * wgt;
    const float* op = base0 + (size_t)s * PARTF + row * 64 + cq * 16;
#pragma unroll
    for (int i = 0; i < 16; ++i) accv[i] += op[i] * wgt;
  }
  float inv = 1.0f / Lt;
  int qblk = e ? NBLK - 1 : 0;
  int tok = qblk * 64 + row;
  bf16* cp = ctx + (size_t)(b * SEQ + tok) * DM + h * DHD + cq * 16;
#pragma unroll
  for (int i = 0; i < 16; ++i) cp[i] = __float2bfloat16(accv[i] * inv);
}

// ---------------- last-layer 2-row GEMV: y[r][col] = act(X[r] @ WT[col] + bias) ----------------
// grid (N/64, 2), 256 thr, 4 threads per output col. ACT: 0 none -> f32 out, 1 gelu -> bf16 out.
template <int ACT>
__global__ __launch_bounds__(256) void k_gemv(
    const bf16* __restrict__ X, size_t xstride, int K,
    const bf16* __restrict__ WT, const float* __restrict__ bias,
    float* __restrict__ Yf, bf16* __restrict__ Yb, int N) {
  const int r = blockIdx.y;
  const int tid = threadIdx.x;
  const int col = blockIdx.x * 64 + (tid >> 2);
  const int t4 = tid & 3;
  const bf16* xp = X + (size_t)r * xstride;
  const bf16* wp = WT + (size_t)col * K;
  float s = 0.f;
  for (int k = t4 * 8; k < K; k += 32) {
    bf16x8 xv = *(const bf16x8*)(xp + k);
    bf16x8 wv = *(const bf16x8*)(wp + k);
#pragma unroll
    for (int i = 0; i < 8; ++i)
      s += b2f((unsigned short)xv[i]) * b2f((unsigned short)wv[i]);
  }
  s += __shfl_xor(s, 1);
  s += __shfl_xor(s, 2);
  if (t4 == 0) {
    float x = s + bias[col];
    if constexpr (ACT == 1) {
      x = 0.5f * x * (1.0f + erff(x * 0.70710678118654752f));
      Yb[(size_t)r * N + col] = __float2bfloat16(x);
    } else {
      Yf[(size_t)r * N + col] = x;
    }
  }
}

// -------------- last-layer 2-row LN: out2[r] = LN(g2[r] + res[r*rstride]) --------------
__global__ __launch_bounds__(128) void k_ln2(
    const float* __restrict__ g2, const bf16* __restrict__ res, size_t rstride,
    const float* __restrict__ g, const float* __restrict__ b, bf16* __restrict__ out2) {
  const int r = threadIdx.x >> 6, lane = threadIdx.x & 63;
  const float* gp = g2 + r * DM;
  const unsigned short* rp = (const unsigned short*)res + (size_t)r * rstride;
  float v[12];
  float s = 0.f, s2 = 0.f;
#pragma unroll
  for (int i = 0; i < 3; ++i) {
    const int c = i * 256 + lane * 4;
    float4 a4 = *(const float4*)(gp + c);
    u16x4 r4 = *(const u16x4*)(rp + c);
    float xs[4] = {a4.x + b2f(r4[0]), a4.y + b2f(r4[1]), a4.z + b2f(r4[2]), a4.w + b2f(r4[3])};
#pragma unroll
    for (int k2 = 0; k2 < 4; ++k2) { v[i * 4 + k2] = xs[k2]; s += xs[k2]; s2 += xs[k2] * xs[k2]; }
  }
#pragma unroll
  for (int off = 1; off < 64; off <<= 1) {
    s += __shfl_xor(s, off);
    s2 += __shfl_xor(s2, off);
  }
  const float mean = s * (1.0f / DM);
  const float var = s2 * (1.0f / DM) - mean * mean;
  const float rs = rsqrtf(var + 1e-12f);
  unsigned short* op = (unsigned short*)out2 + (size_t)r * DM;
#pragma unroll
  for (int i = 0; i < 3; ++i) {
    const int c = i * 256 + lane * 4;
    float4 g4 = *(const float4*)(g + c);
    float4 b4 = *(const float4*)(b + c);
    u16x4 o4;
    o4[0] = f2b((v[i * 4 + 0] - mean) * rs * g4.x + b4.x);
    o4[1] = f2b((v[i * 4 + 1] - mean) * rs * g4.y + b4.y);
    o4[2] = f2b((v[i * 4 + 2] - mean) * rs * g4.z + b4.z);
    o4[3] = f2b((v[i * 4 + 3] - mean) * rs * g4.w + b4.w);
    *(u16x4*)(op + c) = o4;
  }
}

// ----------------------------- classifier: x2 @ Wc + bc -----------------------------
__global__ void k_classifier(const bf16* __restrict__ x2, const float* __restrict__ Wc,
                             const float* __restrict__ bc, float* __restrict__ out) {
  const int tid = threadIdx.x, lane = tid & 63, wv = tid >> 6;
  const int b = wv >> 1, c = wv & 1;
  float s = 0.f;
  for (int d = lane; d < DM; d += 64)
    s += b2f(((const unsigned short*)x2)[b * DM + d]) * Wc[d * NCLS + c];
#pragma unroll
  for (int off = 32; off > 0; off >>= 1) s += __shfl_down(s, off);
  if (lane == 0) out[b * NCLS + c] = s + bc[c];
}

// ----------------------------- host launch -----------------------------
extern "C" void kernel_launch(void* const* d_in, const int* in_sizes, int n_in,
                              void* d_out, int out_size, void* d_ws, size_t ws_size,
                              hipStream_t stream) {
  const float* embeddings = (const float*)d_in[0];
  const float* Wp  = (const float*)d_in[2];
  const float* bp  = (const float*)d_in[3];
  const float* pos = (const float*)d_in[4];
  const float* tokv = (const float*)d_in[5];
  const float* lng = (const float*)d_in[6];
  const float* lnb = (const float*)d_in[7];
  const float* Wq  = (const float*)d_in[8];
  const float* bq  = (const float*)d_in[9];
  const float* Wk  = (const float*)d_in[10];
  const float* bk  = (const float*)d_in[11];
  const float* Wv  = (const float*)d_in[12];
  const float* bv  = (const float*)d_in[13];
  const float* Wo  = (const float*)d_in[14];
  const float* bo  = (const float*)d_in[15];
  const float* l1g = (const float*)d_in[16];
  const float* l1b = (const float*)d_in[17];
  const float* W1  = (const float*)d_in[18];
  const float* b1  = (const float*)d_in[19];
  const float* W2  = (const float*)d_in[20];
  const float* b2  = (const float*)d_in[21];
  const float* l2g = (const float*)d_in[22];
  const float* l2b = (const float*)d_in[23];
  const float* Wc  = (const float*)d_in[24];
  const float* bc  = (const float*)d_in[25];
  const int*  bidx = (const int*)d_in[26];
  (void)in_sizes; (void)n_in; (void)out_size; (void)ws_size;

  char* ws = (char*)d_ws;
  size_t off = 0;
  auto alloc = [&](size_t bytes) -> char* {
    char* p = ws + off;
    off += (bytes + 255) & ~(size_t)255;
    return p;
  };
  bf16*  embB  = (bf16*)alloc((size_t)MR * INPD * 2);
  bf16*  wpT   = (bf16*)alloc((size_t)DM * INPD * 2);
  bf16*  wqkvT = (bf16*)alloc((size_t)QKVN * DM * 2);
  bf16*  woT   = (bf16*)alloc((size_t)DM * DM * 2);
  bf16*  w1T   = (bf16*)alloc((size_t)FFD * DM * 2);
  bf16*  w2T   = (bf16*)alloc((size_t)DM * FFD * 2);
  bf16*  xb    = (bf16*)alloc((size_t)MR * DM * 2);   // residual stream (bf16)
  bf16*  gout  = (bf16*)alloc((size_t)MR * DM * 2);   // raw GEMM out (pre-LN)
  bf16*  qkvB  = (bf16*)alloc((size_t)MR * QKVN * 2); // Q,K sections used
  bf16*  vtB   = (bf16*)alloc((size_t)BATCH * NH * DHD * SEQ * 2);
  bf16*  ctxB  = (bf16*)alloc((size_t)MR * DM * 2);
  bf16*  hB    = (bf16*)alloc((size_t)MR * FFD * 2);
  float* epart = (float*)alloc((size_t)BATCH * NH * 2 * 8 * PARTF * 4);
  float* g2    = (float*)alloc(2 * DM * 4);
  bf16*  xb2   = (bf16*)alloc(2 * DM * 2);
  bf16*  h2    = (bf16*)alloc(2 * FFD * 2);

  // embed: gout = emb @ Wp + bp + pos + tok (bf16); xb = LN(gout)
  k_f32_to_bf16<<<2048, 256, 0, stream>>>(embeddings, embB, MR * INPD);
  k_transpose_one<<<(INPD / 32) * (DM / 32), 256, 0, stream>>>(Wp, wpT, INPD, DM);
  k_gemm<3><<<dim3(DM / 128, MR / 128), 256, 0, stream>>>(embB, wpT, DM, INPD,
      bp, pos, tokv, gout);
  k_ln_res<false><<<MR / 4, 256, 0, stream>>>(gout, gout, lng, lnb, xb);

  for (int l = 0; l < NL - 1; ++l) {
    k_transpose_layer<<<6912, 256, 0, stream>>>(Wq, Wk, Wv, Wo, W1, W2,
        wqkvT, woT, w1T, w2T, l);
    k_gemm_big<0><<<dim3(QKVN / 128, MR / 256), 512, 0, stream>>>(xb, wqkvT, QKVN, DM,
        bq + (size_t)l * DM, bk + (size_t)l * DM, bv + (size_t)l * DM, vtB, qkvB);
    k_attn<<<BATCH * NH * NJOBS, 256, 0, stream>>>(qkvB, vtB, bidx, ctxB, epart, NJOBS, 0);
    k_combine<<<BATCH * NH * 2, 256, 0, stream>>>(epart, ctxB, 2);
    k_gemm<2><<<dim3(DM / 128, MR / 128), 256, 0, stream>>>(ctxB, woT, DM, DM,
        bo + (size_t)l * DM, nullptr, nullptr, gout);
    k_ln_res<true><<<MR / 4, 256, 0, stream>>>(gout, xb,
        l1g + (size_t)l * DM, l1b + (size_t)l * DM, xb);
    k_gemm_big<1><<<dim3(FFD / 128, MR / 256), 512, 0, stream>>>(xb, w1T, FFD, DM,
        b1 + (size_t)l * FFD, nullptr, nullptr, nullptr, hB);
    k_gemm<2><<<dim3(DM / 128, MR / 128), 256, 0, stream>>>(hB, w2T, DM, FFD,
        b2 + (size_t)l * DM, nullptr, nullptr, gout);
    k_ln_res<true><<<MR / 4, 256, 0, stream>>>(gout, xb,
        l2g + (size_t)l * DM, l2b + (size_t)l * DM, xb);
  }

  // ---- last layer (l = 11): classifier reads only tokens {0, 4096} -> row-wise tail on 2 rows
  {
    const int l = NL - 1;
    k_transpose_layer<<<6912, 256, 0, stream>>>(Wq, Wk, Wv, Wo, W1, W2,
        wqkvT, woT, w1T, w2T, l);
    k_gemm_big<0><<<dim3(QKVN / 128, MR / 256), 512, 0, stream>>>(xb, wqkvT, QKVN, DM,
        bq + (size_t)l * DM, bk + (size_t)l * DM, bv + (size_t)l * DM, vtB, qkvB);
    // only edge e=0 (q-block 0 of each batch) is needed: jobs j = 62..69
    k_attn<<<BATCH * NH * 8, 256, 0, stream>>>(qkvB, vtB, bidx, ctxB, epart, 8, 62);
    k_combine<<<BATCH * NH * 1, 256, 0, stream>>>(epart, ctxB, 1);
    // O-proj on rows {0, 4096}
    k_gemv<0><<<dim3(DM / 64, 2), 256, 0, stream>>>(ctxB, (size_t)SEQ * DM, DM,
        woT, bo + (size_t)l * DM, g2, nullptr, DM);
    k_ln2<<<1, 128, 0, stream>>>(g2, xb, (size_t)SEQ * DM,
        l1g + (size_t)l * DM, l1b + (size_t)l * DM, xb2);
    k_gemv<1><<<dim3(FFD / 64, 2), 256, 0, stream>>>(xb2, (size_t)DM, DM,
        w1T, b1 + (size_t)l * FFD, nullptr, h2, FFD);
    k_gemv<0><<<dim3(DM / 64, 2), 256, 0, stream>>>(h2, (size_t)FFD, FFD,
        w2T, b2 + (size_t)l * DM, g2, nullptr, DM);
    k_ln2<<<1, 128, 0, stream>>>(g2, xb2, (size_t)DM,
        l2g + (size_t)l * DM, l2b + (size_t)l * DM, xb2);
  }
  k_classifier<<<1, 256, 0, stream>>>(xb2, Wc, bc, (float*)d_out);
}